// Round 13
// baseline (203.168 us; speedup 1.0000x reference)
//
#include <hip/hip_runtime.h>
#include <math.h>

typedef unsigned short u16;
typedef unsigned int u32;
typedef __attribute__((ext_vector_type(8))) unsigned short us8;
typedef __attribute__((ext_vector_type(8))) __bf16 bf16x8;
typedef __attribute__((ext_vector_type(4))) float f32x4;

#define MFMA16(a, b, c) __builtin_amdgcn_mfma_f32_16x16x32_bf16((a), (b), (c), 0, 0, 0)

static __device__ __forceinline__ float bf2f(u16 u) {
  union { u32 i; float f; } v; v.i = ((u32)u) << 16; return v.f;
}
static __device__ __forceinline__ u16 f2bf(float f) {
  __bf16 h = (__bf16)f;
  return __builtin_bit_cast(u16, h);
}
static __device__ __forceinline__ u32 pk2bf(float lo, float hi) {
  return ((u32)f2bf(hi) << 16) | (u32)f2bf(lo);
}
static __device__ __forceinline__ float lo16(u32 v) {
  union { u32 i; float f; } u; u.i = v << 16; return u.f;
}
static __device__ __forceinline__ float hi16(u32 v) {
  union { u32 i; float f; } u; u.i = v & 0xFFFF0000u; return u.f;
}
static __device__ __forceinline__ bf16x8 ldfrag(const u16* p) {
  us8 v = *reinterpret_cast<const us8*>(p);
  return __builtin_bit_cast(bf16x8, v);
}
// sigmoid-gelu: x * sigmoid(1.702x); exp folded to exp2
static __device__ __forceinline__ float gelu_s(float x) {
  return x * __builtin_amdgcn_rcpf(1.0f + __builtin_amdgcn_exp2f(-2.45564427f * x));
}

#define NTOK 147456  // 384*384
#define NWX 48
#define LOG2E 1.4426950408889634f

// ---------------------------------------------------------------------------
// Prep: transpose weights to bf16 [o][c], expand rel bias (log2-domain),
// repack dwconv weights [9][256]
// ---------------------------------------------------------------------------
__global__ __launch_bounds__(256) void k_prep(
    const float* __restrict__ wq, const float* __restrict__ wkv,
    const float* __restrict__ wproj, const float* __restrict__ w1,
    const float* __restrict__ w2, const float* __restrict__ relb,
    const float* __restrict__ dwk,
    u16* __restrict__ wqkvT, u16* __restrict__ wpT,
    u16* __restrict__ w1T, u16* __restrict__ w2T, float* __restrict__ biasx,
    float* __restrict__ dwkT)
{
  const int idx = blockIdx.x * 256 + threadIdx.x;
  const int NT = 64 * 256;
  for (int i = idx; i < 12288; i += NT) {
    int o = i >> 6, c = i & 63;
    wqkvT[i] = f2bf(o < 64 ? wq[c * 64 + o] : wkv[c * 128 + (o - 64)]);
  }
  for (int i = idx; i < 4096; i += NT) {
    int o = i >> 6, c = i & 63;
    wpT[i] = f2bf(wproj[c * 64 + o]);
  }
  for (int i = idx; i < 16384; i += NT) {
    int o = i >> 6, c = i & 63;
    w1T[i] = f2bf(w1[c * 256 + o]);
  }
  for (int i = idx; i < 16384; i += NT) {
    int o = i >> 8, c2 = i & 255;
    w2T[i] = f2bf(w2[c2 * 64 + o]);
  }
  for (int i = idx; i < 8192; i += NT) {
    int h = i >> 12, r = i & 4095, ii = r >> 6, j = r & 63;
    int dy = (ii >> 3) - (j >> 3) + 7, dx = (ii & 7) - (j & 7) + 7;
    biasx[i] = relb[(dy * 15 + dx) * 2 + h] * LOG2E;   // log2-domain
  }
  for (int i = idx; i < 2304; i += NT) {
    int q = i >> 8, c = i & 255;
    dwkT[i] = dwk[c * 9 + q];
  }
}

// softmax (log2 domain) of 4 tile-scores for one quarter of rows -> Pd (bf16)
static __device__ __forceinline__ void softmax_rows(
    const f32x4* sc, const float* biasrow_base, int i0, int lg, int lr,
    u16* Pd)
{
#pragma unroll
  for (int r = 0; r < 4; ++r) {
    const int i = i0 + lg * 4 + r;
    const float* brow = biasrow_base + i * 64;
    float pv[4];
    float mx = -1e30f;
#pragma unroll
    for (int jt = 0; jt < 4; ++jt) {
      pv[jt] = fmaf(sc[jt][r], 0.2550349f, brow[jt * 16 + lr]);  // SCALE*log2e
      mx = fmaxf(mx, pv[jt]);
    }
#pragma unroll
    for (int off = 1; off < 16; off <<= 1) mx = fmaxf(mx, __shfl_xor(mx, off));
    float sum = 0.f;
#pragma unroll
    for (int jt = 0; jt < 4; ++jt) {
      pv[jt] = __builtin_amdgcn_exp2f(pv[jt] - mx);
      sum += pv[jt];
    }
#pragma unroll
    for (int off = 1; off < 16; off <<= 1) sum += __shfl_xor(sum, off);
    const float inv = __builtin_amdgcn_rcpf(sum);
#pragma unroll
    for (int jt = 0; jt < 4; ++jt)
      Pd[i * 72 + jt * 16 + lr] = f2bf(pv[jt] * inv);
  }
}

// ---------------------------------------------------------------------------
// Kernel 1: LN1 + windowed MHSA + proj + residual -> x1b (bf16),
// plus fused LN2 -> xn (bf16). one block = 1 window, 256 thr, 3 barriers
// ---------------------------------------------------------------------------
__global__ __launch_bounds__(256, 4) void k_attn(
    const float* __restrict__ x,
    const float* __restrict__ n1g, const float* __restrict__ n1b,
    const u16* __restrict__ wqkvT, const float* __restrict__ bq,
    const float* __restrict__ bkv, const float* __restrict__ biasx,
    const u16* __restrict__ wpT, const float* __restrict__ bproj,
    const float* __restrict__ n2g, const float* __restrict__ n2b,
    u16* __restrict__ x1b, u16* __restrict__ xn)
{
  __shared__ u16 xs[64 * 72];    // LN1 out, later P (head 0)
  __shared__ u16 qsm[64 * 72];   // Q, later P (head 1)
  __shared__ u16 ksm[64 * 72];   // K, later O
  __shared__ u16 vT[64 * 72];    // V transposed [ch][token]

  const int tid = threadIdx.x;
  const int wv = tid >> 6;
  const int ln = tid & 63;
  const int lg = ln >> 4, lr = ln & 15;

  const int blk = blockIdx.x;          // 4608 blocks, 1 window each
  const int b = blk / 2304;
  const int rem = blk - b * 2304;
  const int wy = rem / NWX, wx = rem - wy * NWX;

  // ---- load window + LN1 -> xs (4 adjacent lanes own one token) ----
  {
    const int t = tid >> 2, g = tid & 3;
    const int gy = wy * 8 + (t >> 3), gx = wx * 8 + (t & 7);
    const long rowbase = ((long)b * NTOK + gy * 384 + gx) * 64;
    float loc[16];
    float s0 = 0.f, s1 = 0.f;
#pragma unroll
    for (int k = 0; k < 16; k += 4) {
      float4 v4 = *reinterpret_cast<const float4*>(x + rowbase + g * 16 + k);
      loc[k] = v4.x; loc[k + 1] = v4.y; loc[k + 2] = v4.z; loc[k + 3] = v4.w;
    }
#pragma unroll
    for (int k = 0; k < 16; ++k) { s0 += loc[k]; s1 += loc[k] * loc[k]; }
    s0 += __shfl_xor(s0, 1); s0 += __shfl_xor(s0, 2);
    s1 += __shfl_xor(s1, 1); s1 += __shfl_xor(s1, 2);
    const float m = s0 * 0.015625f;
    const float var = s1 * 0.015625f - m * m;
    const float rs = rsqrtf(var + 1e-5f);
#pragma unroll
    for (int k = 0; k < 16; ++k) {
      int c = g * 16 + k;
      xs[t * 72 + c] = f2bf((loc[k] - m) * rs * n1g[c] + n1b[c]);
    }
  }
  __syncthreads();   // barrier 1

  // ---- QKV: 3 n-groups per wave (hoisted B-frags), 4 i-tiles each ----
#pragma unroll
  for (int qq = 0; qq < 3; ++qq) {
    const int grp = 3 * wv + qq;           // 0..11 (wave-uniform)
    const int n0 = grp * 16;
    const int oc = n0 + lr;
    const float bias = (grp < 4) ? bq[oc] : bkv[oc - 64];
    bf16x8 b0 = ldfrag(&wqkvT[oc * 64 + lg * 8]);
    bf16x8 b1 = ldfrag(&wqkvT[oc * 64 + 32 + lg * 8]);
#pragma unroll
    for (int ii = 0; ii < 4; ++ii) {
      const int i0 = ii * 16;
      f32x4 acc = { bias, bias, bias, bias };
      acc = MFMA16(ldfrag(&xs[(i0 + lr) * 72 + lg * 8]), b0, acc);
      acc = MFMA16(ldfrag(&xs[(i0 + lr) * 72 + 32 + lg * 8]), b1, acc);
      const int tok0 = i0 + lg * 4;
      if (grp < 4) {
#pragma unroll
        for (int r = 0; r < 4; ++r) qsm[(tok0 + r) * 72 + oc] = f2bf(acc[r]);
      } else if (grp < 8) {
#pragma unroll
        for (int r = 0; r < 4; ++r) ksm[(tok0 + r) * 72 + (oc - 64)] = f2bf(acc[r]);
      } else {
        u32* dst = reinterpret_cast<u32*>(&vT[(oc - 128) * 72 + tok0]);
        dst[0] = pk2bf(acc[0], acc[1]);
        dst[1] = pk2bf(acc[2], acc[3]);
      }
    }
  }
  __syncthreads();   // barrier 2

  // ---- S (both heads) + softmax + P + PV -- no barriers (wave-private rows) ----
  const int i0 = wv * 16;
  f32x4 oacc[2][2];
  {
    bf16x8 aq0 = ldfrag(&qsm[(i0 + lr) * 72 + lg * 8]);
    bf16x8 aq1 = ldfrag(&qsm[(i0 + lr) * 72 + 32 + lg * 8]);
    f32x4 sc0[4], sc1[4];
#pragma unroll
    for (int jt = 0; jt < 4; ++jt) {
      f32x4 z = {};
      bf16x8 bk0 = ldfrag(&ksm[(jt * 16 + lr) * 72 + lg * 8]);
      bf16x8 bk1 = ldfrag(&ksm[(jt * 16 + lr) * 72 + 32 + lg * 8]);
      sc0[jt] = MFMA16(aq0, bk0, z);
      sc1[jt] = MFMA16(aq1, bk1, z);
    }
    softmax_rows(sc0, biasx, i0, lg, lr, xs);           // P head0 -> xs
    softmax_rows(sc1, biasx + 4096, i0, lg, lr, qsm);   // P head1 -> qsm

    // PV (reads own P rows; vT from barrier-2)
#pragma unroll
    for (int q = 0; q < 2; ++q) {
      f32x4 a0 = {}, a1 = {};
#pragma unroll
      for (int ks = 0; ks < 64; ks += 32) {
        a0 = MFMA16(ldfrag(&xs[(i0 + lr) * 72 + ks + lg * 8]),
                    ldfrag(&vT[(q * 16 + lr) * 72 + ks + lg * 8]), a0);
        a1 = MFMA16(ldfrag(&qsm[(i0 + lr) * 72 + ks + lg * 8]),
                    ldfrag(&vT[(32 + q * 16 + lr) * 72 + ks + lg * 8]), a1);
      }
      oacc[0][q] = a0;
      oacc[1][q] = a1;
    }
  }
  __syncthreads();   // barrier 3: all waves done reading ksm (S phase)

  // ---- O -> ksm (own rows) + early residual prefetch ----
  const int tok0p = i0 + lg * 4;
  const int gy0 = wy * 8 + (tok0p >> 3), gx0 = wx * 8 + (tok0p & 7);
  const long xbase = ((long)b * NTOK + gy0 * 384 + gx0) * 64;  // +64/token (r)

#pragma unroll
  for (int h = 0; h < 2; ++h)
#pragma unroll
    for (int q = 0; q < 2; ++q) {
      const int ch = h * 32 + q * 16 + lr;
#pragma unroll
      for (int r = 0; r < 4; ++r)
        ksm[(i0 + lg * 4 + r) * 72 + ch] = f2bf(oacc[h][q][r]);
    }

  // issue x residual loads now (latency hides under proj MFMAs)
  float xres[4][4];
#pragma unroll
  for (int q = 0; q < 4; ++q) {
    long idx = xbase + q * 16 + lr;
#pragma unroll
    for (int r = 0; r < 4; ++r) { xres[q][r] = x[idx]; idx += 64; }
  }
  // no barrier: proj reads only this wave's own O rows

  // ---- proj + residual -> x1b (bf16), fused LN2 -> xn (bf16) ----
  {
    float vst[4][4];
    float s[4] = {}, sq[4] = {};
#pragma unroll
    for (int q = 0; q < 4; ++q) {
      const int oc = q * 16 + lr;
      const float bp = bproj[oc];
      f32x4 acc = { bp, bp, bp, bp };
#pragma unroll
      for (int ks = 0; ks < 64; ks += 32) {
        bf16x8 ao = ldfrag(&ksm[(i0 + lr) * 72 + ks + lg * 8]);
        bf16x8 bw = ldfrag(&wpT[oc * 64 + ks + lg * 8]);
        acc = MFMA16(ao, bw, acc);
      }
      long idx = xbase + oc;
#pragma unroll
      for (int r = 0; r < 4; ++r) {
        const float v = xres[q][r] + acc[r];
        x1b[idx] = f2bf(v);
        vst[q][r] = v;
        s[r] += v; sq[r] += v * v;
        idx += 64;
      }
    }
    float ng[4], nb[4];
#pragma unroll
    for (int q = 0; q < 4; ++q) { ng[q] = n2g[q * 16 + lr]; nb[q] = n2b[q * 16 + lr]; }
#pragma unroll
    for (int r = 0; r < 4; ++r) {
      float ss = s[r], qq = sq[r];
#pragma unroll
      for (int off = 1; off < 16; off <<= 1) {
        ss += __shfl_xor(ss, off);
        qq += __shfl_xor(qq, off);
      }
      const float m = ss * 0.015625f;
      const float rs = rsqrtf(qq * 0.015625f - m * m + 1e-5f);
      const long idxn = xbase + r * 64 + lr;
#pragma unroll
      for (int q = 0; q < 4; ++q)
        xn[idxn + q * 16] = f2bf((vst[q][r] - m) * rs * ng[q] + nb[q]);
    }
  }
}

// ---------------------------------------------------------------------------
// Kernel 2: stage xn halo + fc1 + gelu + dwconv3x3 + gelu + fc2 + residual
// HID chunked by 64; 38.9KB LDS -> 4 blocks/CU; interior fast path
// ---------------------------------------------------------------------------
__global__ __launch_bounds__(512, 8) void k_mlp(
    const u16* __restrict__ x1b, const u16* __restrict__ xn,
    const u16* __restrict__ w1T, const float* __restrict__ pb1,
    const float* __restrict__ dwkT, const float* __restrict__ dwb,
    const u16* __restrict__ w2T, const float* __restrict__ pb2,
    float* __restrict__ out)
{
  __shared__ u16 xln[112 * 72];    // LN2'd halo tile (bf16); rows>=100 garbage ok
  __shared__ u16 htbT[64 * 102];   // gelu(fc1) chunk, TRANSPOSED [ch][pos]
  __shared__ u16 g2[64 * 72];      // gelu(dwconv) chunk (bf16) [token][ch]
  __shared__ float flag[112];      // boundary blocks only

  const int tid = threadIdx.x;
  const int wave = tid >> 6, ln = tid & 63;
  const int lg = ln >> 4, lr = ln & 15;
  const int blk = blockIdx.x;
  const int b = blk / 2304;
  const int rem = blk - b * 2304;
  const int ty0 = (rem / NWX) * 8, tx0 = (rem - (rem / NWX) * NWX) * 8;
  const bool interior = (ty0 > 0) && (ty0 < 376) && (tx0 > 0) && (tx0 < 376);

  const int hh = ln >> 5, c2 = ln & 31;
  const long hbase = (long)b * NTOK + (ty0 - 1) * 384 + (tx0 - 1);

  if (interior) {
#pragma unroll
    for (int j = 0; j < 7; ++j) {
      const int p = j * 16 + wave * 2 + hh;
      if (p < 100) {
        const int ry = p / 10, rx = p - ry * 10;
        const long tok = hbase + ry * 384 + rx;
        *reinterpret_cast<u32*>(&xln[p * 72 + c2 * 2]) =
            *reinterpret_cast<const u32*>(&xn[tok * 64 + c2 * 2]);
      }
    }
  } else {
    if (tid < 112) {
      float f = 0.f;
      if (tid < 100) {
        const int py = ty0 + tid / 10 - 1, px = tx0 + tid % 10 - 1;
        if (py >= 0 && py < 384 && px >= 0 && px < 384) f = 1.f;
      }
      flag[tid] = f;
    }
#pragma unroll
    for (int j = 0; j < 7; ++j) {
      const int p = j * 16 + wave * 2 + hh;
      if (p < 112) {
        u32 v = 0;
        if (p < 100) {
          const int ry = p / 10, rx = p - ry * 10;
          const int py = ty0 - 1 + ry, px = tx0 - 1 + rx;
          if ((unsigned)py < 384u && (unsigned)px < 384u) {
            const long tok = hbase + ry * 384 + rx;
            v = *reinterpret_cast<const u32*>(&xn[tok * 64 + c2 * 2]);
          }
        }
        *reinterpret_cast<u32*>(&xln[p * 72 + c2 * 2]) = v;
      }
    }
  }
  __syncthreads();   // xln (+flag) ready

  // wave-constant tile coordinates
  const int n0f = (wave & 3) * 16;       // fc1 col-tile base (const per wave)
  const int i0b = (wave >> 2) * 16;      // fc1 row-tile base: 0 or 16
  const int ocf = n0f + lr;
  const int o0  = (wave >> 1) * 16;      // fc2 out-col tile
  const int i0q = ((wave * 2) & 3) * 16; // fc2 row tile base (q=0)
  const int oc2 = o0 + lr;
  const float fc2_b = pb2[oc2];
  f32x4 facc[2] = { { fc2_b, fc2_b, fc2_b, fc2_b }, { fc2_b, fc2_b, fc2_b, fc2_b } };
  float xpre[2][4];   // epilogue residual prefetch (filled at ch==3)

#pragma unroll 1
  for (int ch = 0; ch < 4; ++ch) {
    // ---- fc1 chunk + gelu -> htbT ----
    {
      const u16* wbase = &w1T[(ch * 64 + ocf) * 64 + lg * 8];
      bf16x8 wb0 = ldfrag(wbase);
      bf16x8 wb1 = ldfrag(wbase + 32);
      const float bias1 = pb1[ch * 64 + ocf];
      if (interior) {
#pragma unroll
        for (int k = 0; k < 4; ++k) {
          const int i0 = i0b + k * 32;
          if (i0 < 112) {
            f32x4 acc = { bias1, bias1, bias1, bias1 };
            acc = MFMA16(ldfrag(&xln[(i0 + lr) * 72 + lg * 8]), wb0, acc);
            acc = MFMA16(ldfrag(&xln[(i0 + lr) * 72 + 32 + lg * 8]), wb1, acc);
            const int p0 = i0 + lg * 4;
            if (p0 < 100) {
              u32* dst = reinterpret_cast<u32*>(&htbT[ocf * 102 + p0]);
              dst[0] = pk2bf(gelu_s(acc[0]), gelu_s(acc[1]));
              dst[1] = pk2bf(gelu_s(acc[2]), gelu_s(acc[3]));
            }
          }
        }
      } else {
#pragma unroll
        for (int k = 0; k < 4; ++k) {
          const int i0 = i0b + k * 32;
          if (i0 < 112) {
            f32x4 acc = { bias1, bias1, bias1, bias1 };
            acc = MFMA16(ldfrag(&xln[(i0 + lr) * 72 + lg * 8]), wb0, acc);
            acc = MFMA16(ldfrag(&xln[(i0 + lr) * 72 + 32 + lg * 8]), wb1, acc);
            const int p0 = i0 + lg * 4;
            if (p0 < 100) {
              float g0 = gelu_s(acc[0]) * flag[p0 + 0];
              float g1 = gelu_s(acc[1]) * flag[p0 + 1];
              float g2v = gelu_s(acc[2]) * flag[p0 + 2];
              float g3 = gelu_s(acc[3]) * flag[p0 + 3];
              u32* dst = reinterpret_cast<u32*>(&htbT[ocf * 102 + p0]);
              dst[0] = pk2bf(g0, g1);
              dst[1] = pk2bf(g2v, g3);
            }
          }
        }
      }
    }
    __syncthreads();

    // ---- dwconv 3x3 + gelu -> g2 (wave = token row, lane = channel) ----
    {
      const int gch = ch * 64 + ln;
      float wk[9];
      const float db = dwb[gch];
#pragma unroll
      for (int q = 0; q < 9; ++q) wk[q] = dwkT[q * 256 + gch];   // coalesced
      const u16* rowbase = &htbT[ln * 102];
      const u32* r0 = reinterpret_cast<const u32*>(rowbase + (wave + 0) * 10);
      const u32* r1 = reinterpret_cast<const u32*>(rowbase + (wave + 1) * 10);
      const u32* r2 = reinterpret_cast<const u32*>(rowbase + (wave + 2) * 10);
      u32 v;
      float a0,b0,c0,d0, a1,b1,c1,d1, a2,b2,c2,d2;
      v = r0[0]; a0 = lo16(v); b0 = hi16(v);
      v = r0[1]; c0 = lo16(v); d0 = hi16(v);
      v = r1[0]; a1 = lo16(v); b1 = hi16(v);
      v = r1[1]; c1 = lo16(v); d1 = hi16(v);
      v = r2[0]; a2 = lo16(v); b2 = hi16(v);
      v = r2[1]; c2 = lo16(v); d2 = hi16(v);
#pragma unroll
      for (int s = 0; s < 4; ++s) {
        float e0 = db + a0 * wk[0] + b0 * wk[1] + c0 * wk[2]
                      + a1 * wk[3] + b1 * wk[4] + c1 * wk[5]
                      + a2 * wk[6] + b2 * wk[7] + c2 * wk[8];
        float e1 = db + b0 * wk[0] + c0 * wk[1] + d0 * wk[2]
                      + b1 * wk[3] + c1 * wk[4] + d1 * wk[5]
                      + b2 * wk[6] + c2 * wk[7] + d2 * wk[8];
        g2[(wave * 8 + 2 * s) * 72 + ln]     = f2bf(gelu_s(e0));
        g2[(wave * 8 + 2 * s + 1) * 72 + ln] = f2bf(gelu_s(e1));
        if (s < 3) {
          v = r0[s + 2]; a0 = c0; b0 = d0; c0 = lo16(v); d0 = hi16(v);
          v = r1[s + 2]; a1 = c1; b1 = d1; c1 = lo16(v); d1 = hi16(v);
          v = r2[s + 2]; a2 = c2; b2 = d2; c2 = lo16(v); d2 = hi16(v);
        }
      }
    }
    __syncthreads();

    // ---- last chunk: prefetch epilogue residuals (hide under fc2 MFMAs) ----
    if (ch == 3) {
#pragma unroll
      for (int q = 0; q < 2; ++q) {
        const int tok0 = i0q + q * 16 + lg * 4;
        const int gy = ty0 + (tok0 >> 3), gx = tx0 + (tok0 & 7);
        long idx = ((long)b * NTOK + gy * 384 + gx) * 64 + oc2;
#pragma unroll
        for (int r = 0; r < 4; ++r) { xpre[q][r] = bf2f(x1b[idx]); idx += 64; }
      }
    }

    // ---- fc2 partial accumulate (B-frags hoisted, shared by q=0,1) ----
    {
      const u16* wbase2 = &w2T[oc2 * 256 + ch * 64 + lg * 8];
      bf16x8 bw0 = ldfrag(wbase2);
      bf16x8 bw1 = ldfrag(wbase2 + 32);
#pragma unroll
      for (int q = 0; q < 2; ++q) {
        const int i0 = i0q + q * 16;
        bf16x8 ag0 = ldfrag(&g2[(i0 + lr) * 72 + lg * 8]);
        bf16x8 ag1 = ldfrag(&g2[(i0 + lr) * 72 + 32 + lg * 8]);
        facc[q] = MFMA16(ag0, bw0, facc[q]);
        facc[q] = MFMA16(ag1, bw1, facc[q]);
      }
    }
  }

  // ---- epilogue: + bf16 residual (prefetched) -> out ----
#pragma unroll
  for (int q = 0; q < 2; ++q) {
    const int tok0 = i0q + q * 16 + lg * 4;
    const int gy = ty0 + (tok0 >> 3), gx = tx0 + (tok0 & 7);
    long idx = ((long)b * NTOK + gy * 384 + gx) * 64 + oc2;
#pragma unroll
    for (int r = 0; r < 4; ++r) {
      out[idx] = xpre[q][r] + facc[q][r];
      idx += 64;
    }
  }
}

extern "C" void kernel_launch(void* const* d_in, const int* in_sizes, int n_in,
                              void* d_out, int out_size, void* d_ws, size_t ws_size,
                              hipStream_t stream) {
  const float* x     = (const float*)d_in[0];
  const float* n1g   = (const float*)d_in[1];
  const float* n1b   = (const float*)d_in[2];
  const float* wq    = (const float*)d_in[3];
  const float* bq    = (const float*)d_in[4];
  const float* wkv   = (const float*)d_in[5];
  const float* bkv   = (const float*)d_in[6];
  const float* relb  = (const float*)d_in[7];
  const float* wproj = (const float*)d_in[8];
  const float* bproj = (const float*)d_in[9];
  const float* n2g   = (const float*)d_in[10];
  const float* n2b   = (const float*)d_in[11];
  const float* w1    = (const float*)d_in[12];
  const float* b1    = (const float*)d_in[13];
  const float* dwk   = (const float*)d_in[14];
  const float* dwb   = (const float*)d_in[15];
  const float* w2    = (const float*)d_in[16];
  const float* b2    = (const float*)d_in[17];

  char* ws = (char*)d_ws;
  u16*    wqkvT = (u16*)ws;                    //    24576 B
  u16*    wpT   = (u16*)(ws + 24576);          //     8192 B
  u16*    w1T   = (u16*)(ws + 32768);          //    32768 B
  u16*    w2T   = (u16*)(ws + 65536);          //    32768 B
  float*  biasx = (float*)(ws + 98304);        //    32768 B
  float*  dwkT  = (float*)(ws + 131072);       //     9216 B (pad to 16384)
  u16*    x1b   = (u16*)(ws + 147456);         // 37748736 B (bf16 residual)
  u16*    xn    = (u16*)(ws + 37896192);       // 37748736 B (bf16 LN2 out)
  float*  outp  = (float*)d_out;               // total ws use ~75.6 MB

  k_prep<<<64, 256, 0, stream>>>(wq, wkv, wproj, w1, w2, relb, dwk,
                                 wqkvT, wpT, w1T, w2T, biasx, dwkT);
  k_attn<<<4608, 256, 0, stream>>>(x, n1g, n1b, wqkvT, bq, bkv, biasx, wpT, bproj,
                                   n2g, n2b, x1b, xn);
  k_mlp<<<4608, 512, 0, stream>>>(x1b, xn, w1T, b1, dwkT, dwb, w2T, b2, outp);
}

// Round 14
// 189.284 us; speedup vs baseline: 1.0734x; 1.0734x over previous
//
#include <hip/hip_runtime.h>
#include <math.h>

typedef unsigned short u16;
typedef unsigned int u32;
typedef __attribute__((ext_vector_type(8))) unsigned short us8;
typedef __attribute__((ext_vector_type(8))) __bf16 bf16x8;
typedef __attribute__((ext_vector_type(4))) float f32x4;

#define MFMA16(a, b, c) __builtin_amdgcn_mfma_f32_16x16x32_bf16((a), (b), (c), 0, 0, 0)

static __device__ __forceinline__ float bf2f(u16 u) {
  union { u32 i; float f; } v; v.i = ((u32)u) << 16; return v.f;
}
static __device__ __forceinline__ u16 f2bf(float f) {
  __bf16 h = (__bf16)f;
  return __builtin_bit_cast(u16, h);
}
static __device__ __forceinline__ u32 pk2bf(float lo, float hi) {
  return ((u32)f2bf(hi) << 16) | (u32)f2bf(lo);
}
static __device__ __forceinline__ float lo16(u32 v) {
  union { u32 i; float f; } u; u.i = v << 16; return u.f;
}
static __device__ __forceinline__ float hi16(u32 v) {
  union { u32 i; float f; } u; u.i = v & 0xFFFF0000u; return u.f;
}
static __device__ __forceinline__ bf16x8 ldfrag(const u16* p) {
  us8 v = *reinterpret_cast<const us8*>(p);
  return __builtin_bit_cast(bf16x8, v);
}
// sigmoid-gelu: x * sigmoid(1.702x); exp folded to exp2
static __device__ __forceinline__ float gelu_s(float x) {
  return x * __builtin_amdgcn_rcpf(1.0f + __builtin_amdgcn_exp2f(-2.45564427f * x));
}

#define NTOK 147456  // 384*384
#define NWX 48
#define LOG2E 1.4426950408889634f

// ---------------------------------------------------------------------------
// Prep: transpose weights to bf16 [o][c], expand rel bias (log2-domain),
// repack dwconv weights [9][256]
// ---------------------------------------------------------------------------
__global__ __launch_bounds__(256) void k_prep(
    const float* __restrict__ wq, const float* __restrict__ wkv,
    const float* __restrict__ wproj, const float* __restrict__ w1,
    const float* __restrict__ w2, const float* __restrict__ relb,
    const float* __restrict__ dwk,
    u16* __restrict__ wqkvT, u16* __restrict__ wpT,
    u16* __restrict__ w1T, u16* __restrict__ w2T, float* __restrict__ biasx,
    float* __restrict__ dwkT)
{
  const int idx = blockIdx.x * 256 + threadIdx.x;
  const int NT = 64 * 256;
  for (int i = idx; i < 12288; i += NT) {
    int o = i >> 6, c = i & 63;
    wqkvT[i] = f2bf(o < 64 ? wq[c * 64 + o] : wkv[c * 128 + (o - 64)]);
  }
  for (int i = idx; i < 4096; i += NT) {
    int o = i >> 6, c = i & 63;
    wpT[i] = f2bf(wproj[c * 64 + o]);
  }
  for (int i = idx; i < 16384; i += NT) {
    int o = i >> 6, c = i & 63;
    w1T[i] = f2bf(w1[c * 256 + o]);
  }
  for (int i = idx; i < 16384; i += NT) {
    int o = i >> 8, c2 = i & 255;
    w2T[i] = f2bf(w2[c2 * 64 + o]);
  }
  for (int i = idx; i < 8192; i += NT) {
    int h = i >> 12, r = i & 4095, ii = r >> 6, j = r & 63;
    int dy = (ii >> 3) - (j >> 3) + 7, dx = (ii & 7) - (j & 7) + 7;
    biasx[i] = relb[(dy * 15 + dx) * 2 + h] * LOG2E;   // log2-domain
  }
  for (int i = idx; i < 2304; i += NT) {
    int q = i >> 8, c = i & 255;
    dwkT[i] = dwk[c * 9 + q];
  }
}

// softmax (log2 domain) of 4 tile-scores for one quarter of rows -> Pd (bf16)
static __device__ __forceinline__ void softmax_rows(
    const f32x4* sc, const float* biasrow_base, int i0, int lg, int lr,
    u16* Pd)
{
#pragma unroll
  for (int r = 0; r < 4; ++r) {
    const int i = i0 + lg * 4 + r;
    const float* brow = biasrow_base + i * 64;
    float pv[4];
    float mx = -1e30f;
#pragma unroll
    for (int jt = 0; jt < 4; ++jt) {
      pv[jt] = fmaf(sc[jt][r], 0.2550349f, brow[jt * 16 + lr]);  // SCALE*log2e
      mx = fmaxf(mx, pv[jt]);
    }
#pragma unroll
    for (int off = 1; off < 16; off <<= 1) mx = fmaxf(mx, __shfl_xor(mx, off));
    float sum = 0.f;
#pragma unroll
    for (int jt = 0; jt < 4; ++jt) {
      pv[jt] = __builtin_amdgcn_exp2f(pv[jt] - mx);
      sum += pv[jt];
    }
#pragma unroll
    for (int off = 1; off < 16; off <<= 1) sum += __shfl_xor(sum, off);
    const float inv = __builtin_amdgcn_rcpf(sum);
#pragma unroll
    for (int jt = 0; jt < 4; ++jt)
      Pd[i * 72 + jt * 16 + lr] = f2bf(pv[jt] * inv);
  }
}

// ---------------------------------------------------------------------------
// Kernel 1: LN1 + windowed MHSA + proj + residual -> x1b (bf16),
// plus fused LN2 -> xn (bf16). one block = 1 window, 256 thr, 3 barriers
// ---------------------------------------------------------------------------
__global__ __launch_bounds__(256, 4) void k_attn(
    const float* __restrict__ x,
    const float* __restrict__ n1g, const float* __restrict__ n1b,
    const u16* __restrict__ wqkvT, const float* __restrict__ bq,
    const float* __restrict__ bkv, const float* __restrict__ biasx,
    const u16* __restrict__ wpT, const float* __restrict__ bproj,
    const float* __restrict__ n2g, const float* __restrict__ n2b,
    u16* __restrict__ x1b, u16* __restrict__ xn)
{
  __shared__ u16 xs[64 * 72];    // LN1 out, later P (head 0)
  __shared__ u16 qsm[64 * 72];   // Q, later P (head 1)
  __shared__ u16 ksm[64 * 72];   // K, later O
  __shared__ u16 vT[64 * 72];    // V transposed [ch][token]

  const int tid = threadIdx.x;
  const int wv = tid >> 6;
  const int ln = tid & 63;
  const int lg = ln >> 4, lr = ln & 15;

  const int blk = blockIdx.x;          // 4608 blocks, 1 window each
  const int b = blk / 2304;
  const int rem = blk - b * 2304;
  const int wy = rem / NWX, wx = rem - wy * NWX;

  // ---- load window + LN1 -> xs (4 adjacent lanes own one token) ----
  {
    const int t = tid >> 2, g = tid & 3;
    const int gy = wy * 8 + (t >> 3), gx = wx * 8 + (t & 7);
    const long rowbase = ((long)b * NTOK + gy * 384 + gx) * 64;
    float loc[16];
    float s0 = 0.f, s1 = 0.f;
#pragma unroll
    for (int k = 0; k < 16; k += 4) {
      float4 v4 = *reinterpret_cast<const float4*>(x + rowbase + g * 16 + k);
      loc[k] = v4.x; loc[k + 1] = v4.y; loc[k + 2] = v4.z; loc[k + 3] = v4.w;
    }
#pragma unroll
    for (int k = 0; k < 16; ++k) { s0 += loc[k]; s1 += loc[k] * loc[k]; }
    s0 += __shfl_xor(s0, 1); s0 += __shfl_xor(s0, 2);
    s1 += __shfl_xor(s1, 1); s1 += __shfl_xor(s1, 2);
    const float m = s0 * 0.015625f;
    const float var = s1 * 0.015625f - m * m;
    const float rs = rsqrtf(var + 1e-5f);
#pragma unroll
    for (int k = 0; k < 16; ++k) {
      int c = g * 16 + k;
      xs[t * 72 + c] = f2bf((loc[k] - m) * rs * n1g[c] + n1b[c]);
    }
  }
  __syncthreads();   // barrier 1

  // ---- QKV: 3 n-groups per wave (hoisted B-frags), 4 i-tiles each ----
#pragma unroll
  for (int qq = 0; qq < 3; ++qq) {
    const int grp = 3 * wv + qq;           // 0..11 (wave-uniform)
    const int n0 = grp * 16;
    const int oc = n0 + lr;
    const float bias = (grp < 4) ? bq[oc] : bkv[oc - 64];
    bf16x8 b0 = ldfrag(&wqkvT[oc * 64 + lg * 8]);
    bf16x8 b1 = ldfrag(&wqkvT[oc * 64 + 32 + lg * 8]);
#pragma unroll
    for (int ii = 0; ii < 4; ++ii) {
      const int i0 = ii * 16;
      f32x4 acc = { bias, bias, bias, bias };
      acc = MFMA16(ldfrag(&xs[(i0 + lr) * 72 + lg * 8]), b0, acc);
      acc = MFMA16(ldfrag(&xs[(i0 + lr) * 72 + 32 + lg * 8]), b1, acc);
      const int tok0 = i0 + lg * 4;
      if (grp < 4) {
#pragma unroll
        for (int r = 0; r < 4; ++r) qsm[(tok0 + r) * 72 + oc] = f2bf(acc[r]);
      } else if (grp < 8) {
#pragma unroll
        for (int r = 0; r < 4; ++r) ksm[(tok0 + r) * 72 + (oc - 64)] = f2bf(acc[r]);
      } else {
        u32* dst = reinterpret_cast<u32*>(&vT[(oc - 128) * 72 + tok0]);
        dst[0] = pk2bf(acc[0], acc[1]);
        dst[1] = pk2bf(acc[2], acc[3]);
      }
    }
  }
  __syncthreads();   // barrier 2

  // ---- S (both heads) + softmax + P + PV -- no barriers (wave-private rows) ----
  const int i0 = wv * 16;
  f32x4 oacc[2][2];
  {
    bf16x8 aq0 = ldfrag(&qsm[(i0 + lr) * 72 + lg * 8]);
    bf16x8 aq1 = ldfrag(&qsm[(i0 + lr) * 72 + 32 + lg * 8]);
    f32x4 sc0[4], sc1[4];
#pragma unroll
    for (int jt = 0; jt < 4; ++jt) {
      f32x4 z = {};
      bf16x8 bk0 = ldfrag(&ksm[(jt * 16 + lr) * 72 + lg * 8]);
      bf16x8 bk1 = ldfrag(&ksm[(jt * 16 + lr) * 72 + 32 + lg * 8]);
      sc0[jt] = MFMA16(aq0, bk0, z);
      sc1[jt] = MFMA16(aq1, bk1, z);
    }
    softmax_rows(sc0, biasx, i0, lg, lr, xs);           // P head0 -> xs
    softmax_rows(sc1, biasx + 4096, i0, lg, lr, qsm);   // P head1 -> qsm

    // PV (reads own P rows; vT from barrier-2)
#pragma unroll
    for (int q = 0; q < 2; ++q) {
      f32x4 a0 = {}, a1 = {};
#pragma unroll
      for (int ks = 0; ks < 64; ks += 32) {
        a0 = MFMA16(ldfrag(&xs[(i0 + lr) * 72 + ks + lg * 8]),
                    ldfrag(&vT[(q * 16 + lr) * 72 + ks + lg * 8]), a0);
        a1 = MFMA16(ldfrag(&qsm[(i0 + lr) * 72 + ks + lg * 8]),
                    ldfrag(&vT[(32 + q * 16 + lr) * 72 + ks + lg * 8]), a1);
      }
      oacc[0][q] = a0;
      oacc[1][q] = a1;
    }
  }
  __syncthreads();   // barrier 3: all waves done reading ksm (S phase)

  // ---- O -> ksm (own rows) + early residual prefetch ----
  const int tok0p = i0 + lg * 4;
  const int gy0 = wy * 8 + (tok0p >> 3), gx0 = wx * 8 + (tok0p & 7);
  const long xbase = ((long)b * NTOK + gy0 * 384 + gx0) * 64;  // +64/token (r)

#pragma unroll
  for (int h = 0; h < 2; ++h)
#pragma unroll
    for (int q = 0; q < 2; ++q) {
      const int ch = h * 32 + q * 16 + lr;
#pragma unroll
      for (int r = 0; r < 4; ++r)
        ksm[(i0 + lg * 4 + r) * 72 + ch] = f2bf(oacc[h][q][r]);
    }

  // issue x residual loads now (latency hides under proj MFMAs)
  float xres[4][4];
#pragma unroll
  for (int q = 0; q < 4; ++q) {
    long idx = xbase + q * 16 + lr;
#pragma unroll
    for (int r = 0; r < 4; ++r) { xres[q][r] = x[idx]; idx += 64; }
  }
  // no barrier: proj reads only this wave's own O rows

  // ---- proj + residual -> x1b (bf16), fused LN2 -> xn (bf16) ----
  {
    float vst[4][4];
    float s[4] = {}, sq[4] = {};
#pragma unroll
    for (int q = 0; q < 4; ++q) {
      const int oc = q * 16 + lr;
      const float bp = bproj[oc];
      f32x4 acc = { bp, bp, bp, bp };
#pragma unroll
      for (int ks = 0; ks < 64; ks += 32) {
        bf16x8 ao = ldfrag(&ksm[(i0 + lr) * 72 + ks + lg * 8]);
        bf16x8 bw = ldfrag(&wpT[oc * 64 + ks + lg * 8]);
        acc = MFMA16(ao, bw, acc);
      }
      long idx = xbase + oc;
#pragma unroll
      for (int r = 0; r < 4; ++r) {
        const float v = xres[q][r] + acc[r];
        x1b[idx] = f2bf(v);
        vst[q][r] = v;
        s[r] += v; sq[r] += v * v;
        idx += 64;
      }
    }
    float ng[4], nb[4];
#pragma unroll
    for (int q = 0; q < 4; ++q) { ng[q] = n2g[q * 16 + lr]; nb[q] = n2b[q * 16 + lr]; }
#pragma unroll
    for (int r = 0; r < 4; ++r) {
      float ss = s[r], qq = sq[r];
#pragma unroll
      for (int off = 1; off < 16; off <<= 1) {
        ss += __shfl_xor(ss, off);
        qq += __shfl_xor(qq, off);
      }
      const float m = ss * 0.015625f;
      const float rs = rsqrtf(qq * 0.015625f - m * m + 1e-5f);
      const long idxn = xbase + r * 64 + lr;
#pragma unroll
      for (int q = 0; q < 4; ++q)
        xn[idxn + q * 16] = f2bf((vst[q][r] - m) * rs * ng[q] + nb[q]);
    }
  }
}

// ---------------------------------------------------------------------------
// Kernel 2: stage xn halo + fc1 + gelu + dwconv3x3 + gelu + fc2 + residual
// HID chunked by 64; 38.9KB LDS -> 4 blocks/CU; interior fast path
// ---------------------------------------------------------------------------
__global__ __launch_bounds__(512, 8) void k_mlp(
    const u16* __restrict__ x1b, const u16* __restrict__ xn,
    const u16* __restrict__ w1T, const float* __restrict__ pb1,
    const float* __restrict__ dwkT, const float* __restrict__ dwb,
    const u16* __restrict__ w2T, const float* __restrict__ pb2,
    float* __restrict__ out)
{
  __shared__ u16 xln[112 * 72];    // LN2'd halo tile (bf16); rows>=100 garbage ok
  __shared__ u16 htbT[64 * 102];   // gelu(fc1) chunk, TRANSPOSED [ch][pos]
  __shared__ u16 g2[64 * 72];      // gelu(dwconv) chunk (bf16) [token][ch]
  __shared__ float flag[112];      // boundary blocks only

  const int tid = threadIdx.x;
  const int wave = tid >> 6, ln = tid & 63;
  const int lg = ln >> 4, lr = ln & 15;
  const int blk = blockIdx.x;
  const int b = blk / 2304;
  const int rem = blk - b * 2304;
  const int ty0 = (rem / NWX) * 8, tx0 = (rem - (rem / NWX) * NWX) * 8;
  const bool interior = (ty0 > 0) && (ty0 < 376) && (tx0 > 0) && (tx0 < 376);

  const int hh = ln >> 5, c2 = ln & 31;
  const long hbase = (long)b * NTOK + (ty0 - 1) * 384 + (tx0 - 1);

  if (interior) {
#pragma unroll
    for (int j = 0; j < 7; ++j) {
      const int p = j * 16 + wave * 2 + hh;
      if (p < 100) {
        const int ry = p / 10, rx = p - ry * 10;
        const long tok = hbase + ry * 384 + rx;
        *reinterpret_cast<u32*>(&xln[p * 72 + c2 * 2]) =
            *reinterpret_cast<const u32*>(&xn[tok * 64 + c2 * 2]);
      }
    }
  } else {
    if (tid < 112) {
      float f = 0.f;
      if (tid < 100) {
        const int py = ty0 + tid / 10 - 1, px = tx0 + tid % 10 - 1;
        if (py >= 0 && py < 384 && px >= 0 && px < 384) f = 1.f;
      }
      flag[tid] = f;
    }
#pragma unroll
    for (int j = 0; j < 7; ++j) {
      const int p = j * 16 + wave * 2 + hh;
      if (p < 112) {
        u32 v = 0;
        if (p < 100) {
          const int ry = p / 10, rx = p - ry * 10;
          const int py = ty0 - 1 + ry, px = tx0 - 1 + rx;
          if ((unsigned)py < 384u && (unsigned)px < 384u) {
            const long tok = hbase + ry * 384 + rx;
            v = *reinterpret_cast<const u32*>(&xn[tok * 64 + c2 * 2]);
          }
        }
        *reinterpret_cast<u32*>(&xln[p * 72 + c2 * 2]) = v;
      }
    }
  }
  __syncthreads();   // xln (+flag) ready

  // wave-constant tile coordinates
  const int n0f = (wave & 3) * 16;       // fc1 col-tile base (const per wave)
  const int i0b = (wave >> 2) * 16;      // fc1 row-tile base: 0 or 16
  const int ocf = n0f + lr;
  const int o0  = (wave >> 1) * 16;      // fc2 out-col tile
  const int i0q = ((wave * 2) & 3) * 16; // fc2 row tile base (q=0)
  const int oc2 = o0 + lr;
  const float fc2_b = pb2[oc2];
  f32x4 facc[2] = { { fc2_b, fc2_b, fc2_b, fc2_b }, { fc2_b, fc2_b, fc2_b, fc2_b } };

#pragma unroll 1
  for (int ch = 0; ch < 4; ++ch) {
    // ---- fc1 chunk + gelu -> htbT ----
    {
      const u16* wbase = &w1T[(ch * 64 + ocf) * 64 + lg * 8];
      bf16x8 wb0 = ldfrag(wbase);
      bf16x8 wb1 = ldfrag(wbase + 32);
      const float bias1 = pb1[ch * 64 + ocf];
      if (interior) {
#pragma unroll
        for (int k = 0; k < 4; ++k) {
          const int i0 = i0b + k * 32;
          if (i0 < 112) {
            f32x4 acc = { bias1, bias1, bias1, bias1 };
            acc = MFMA16(ldfrag(&xln[(i0 + lr) * 72 + lg * 8]), wb0, acc);
            acc = MFMA16(ldfrag(&xln[(i0 + lr) * 72 + 32 + lg * 8]), wb1, acc);
            const int p0 = i0 + lg * 4;
            if (p0 < 100) {
              u32* dst = reinterpret_cast<u32*>(&htbT[ocf * 102 + p0]);
              dst[0] = pk2bf(gelu_s(acc[0]), gelu_s(acc[1]));
              dst[1] = pk2bf(gelu_s(acc[2]), gelu_s(acc[3]));
            }
          }
        }
      } else {
#pragma unroll
        for (int k = 0; k < 4; ++k) {
          const int i0 = i0b + k * 32;
          if (i0 < 112) {
            f32x4 acc = { bias1, bias1, bias1, bias1 };
            acc = MFMA16(ldfrag(&xln[(i0 + lr) * 72 + lg * 8]), wb0, acc);
            acc = MFMA16(ldfrag(&xln[(i0 + lr) * 72 + 32 + lg * 8]), wb1, acc);
            const int p0 = i0 + lg * 4;
            if (p0 < 100) {
              float g0 = gelu_s(acc[0]) * flag[p0 + 0];
              float g1 = gelu_s(acc[1]) * flag[p0 + 1];
              float g2v = gelu_s(acc[2]) * flag[p0 + 2];
              float g3 = gelu_s(acc[3]) * flag[p0 + 3];
              u32* dst = reinterpret_cast<u32*>(&htbT[ocf * 102 + p0]);
              dst[0] = pk2bf(g0, g1);
              dst[1] = pk2bf(g2v, g3);
            }
          }
        }
      }
    }
    __syncthreads();

    // ---- dwconv 3x3 + gelu -> g2 (wave = token row, lane = channel) ----
    {
      const int gch = ch * 64 + ln;
      float wk[9];
      const float db = dwb[gch];
#pragma unroll
      for (int q = 0; q < 9; ++q) wk[q] = dwkT[q * 256 + gch];   // coalesced
      const u16* rowbase = &htbT[ln * 102];
      const u32* r0 = reinterpret_cast<const u32*>(rowbase + (wave + 0) * 10);
      const u32* r1 = reinterpret_cast<const u32*>(rowbase + (wave + 1) * 10);
      const u32* r2 = reinterpret_cast<const u32*>(rowbase + (wave + 2) * 10);
      u32 v;
      float a0,b0,c0,d0, a1,b1,c1,d1, a2,b2,c2,d2;
      v = r0[0]; a0 = lo16(v); b0 = hi16(v);
      v = r0[1]; c0 = lo16(v); d0 = hi16(v);
      v = r1[0]; a1 = lo16(v); b1 = hi16(v);
      v = r1[1]; c1 = lo16(v); d1 = hi16(v);
      v = r2[0]; a2 = lo16(v); b2 = hi16(v);
      v = r2[1]; c2 = lo16(v); d2 = hi16(v);
#pragma unroll
      for (int s = 0; s < 4; ++s) {
        float e0 = db + a0 * wk[0] + b0 * wk[1] + c0 * wk[2]
                      + a1 * wk[3] + b1 * wk[4] + c1 * wk[5]
                      + a2 * wk[6] + b2 * wk[7] + c2 * wk[8];
        float e1 = db + b0 * wk[0] + c0 * wk[1] + d0 * wk[2]
                      + b1 * wk[3] + c1 * wk[4] + d1 * wk[5]
                      + b2 * wk[6] + c2 * wk[7] + d2 * wk[8];
        g2[(wave * 8 + 2 * s) * 72 + ln]     = f2bf(gelu_s(e0));
        g2[(wave * 8 + 2 * s + 1) * 72 + ln] = f2bf(gelu_s(e1));
        if (s < 3) {
          v = r0[s + 2]; a0 = c0; b0 = d0; c0 = lo16(v); d0 = hi16(v);
          v = r1[s + 2]; a1 = c1; b1 = d1; c1 = lo16(v); d1 = hi16(v);
          v = r2[s + 2]; a2 = c2; b2 = d2; c2 = lo16(v); d2 = hi16(v);
        }
      }
    }
    __syncthreads();

    // ---- fc2 partial accumulate (B-frags hoisted, shared by q=0,1) ----
    {
      const u16* wbase2 = &w2T[oc2 * 256 + ch * 64 + lg * 8];
      bf16x8 bw0 = ldfrag(wbase2);
      bf16x8 bw1 = ldfrag(wbase2 + 32);
#pragma unroll
      for (int q = 0; q < 2; ++q) {
        const int i0 = i0q + q * 16;
        bf16x8 ag0 = ldfrag(&g2[(i0 + lr) * 72 + lg * 8]);
        bf16x8 ag1 = ldfrag(&g2[(i0 + lr) * 72 + 32 + lg * 8]);
        facc[q] = MFMA16(ag0, bw0, facc[q]);
        facc[q] = MFMA16(ag1, bw1, facc[q]);
      }
    }
  }

  // ---- epilogue: + bf16 residual -> out ----
#pragma unroll
  for (int q = 0; q < 2; ++q) {
    const int tok0 = i0q + q * 16 + lg * 4;
    const int gy = ty0 + (tok0 >> 3), gx = tx0 + (tok0 & 7);
    long idx = ((long)b * NTOK + gy * 384 + gx) * 64 + oc2;
#pragma unroll
    for (int r = 0; r < 4; ++r) {
      out[idx] = bf2f(x1b[idx]) + facc[q][r];
      idx += 64;
    }
  }
}

extern "C" void kernel_launch(void* const* d_in, const int* in_sizes, int n_in,
                              void* d_out, int out_size, void* d_ws, size_t ws_size,
                              hipStream_t stream) {
  const float* x     = (const float*)d_in[0];
  const float* n1g   = (const float*)d_in[1];
  const float* n1b   = (const float*)d_in[2];
  const float* wq    = (const float*)d_in[3];
  const float* bq    = (const float*)d_in[4];
  const float* wkv   = (const float*)d_in[5];
  const float* bkv   = (const float*)d_in[6];
  const float* relb  = (const float*)d_in[7];
  const float* wproj = (const float*)d_in[8];
  const float* bproj = (const float*)d_in[9];
  const float* n2g   = (const float*)d_in[10];
  const float* n2b   = (const float*)d_in[11];
  const float* w1    = (const float*)d_in[12];
  const float* b1    = (const float*)d_in[13];
  const float* dwk   = (const float*)d_in[14];
  const float* dwb   = (const float*)d_in[15];
  const float* w2    = (const float*)d_in[16];
  const float* b2    = (const float*)d_in[17];

  char* ws = (char*)d_ws;
  u16*    wqkvT = (u16*)ws;                    //    24576 B
  u16*    wpT   = (u16*)(ws + 24576);          //     8192 B
  u16*    w1T   = (u16*)(ws + 32768);          //    32768 B
  u16*    w2T   = (u16*)(ws + 65536);          //    32768 B
  float*  biasx = (float*)(ws + 98304);        //    32768 B
  float*  dwkT  = (float*)(ws + 131072);       //     9216 B (pad to 16384)
  u16*    x1b   = (u16*)(ws + 147456);         // 37748736 B (bf16 residual)
  u16*    xn    = (u16*)(ws + 37896192);       // 37748736 B (bf16 LN2 out)
  float*  outp  = (float*)d_out;               // total ws use ~75.6 MB

  k_prep<<<64, 256, 0, stream>>>(wq, wkv, wproj, w1, w2, relb, dwk,
                                 wqkvT, wpT, w1T, w2T, biasx, dwkT);
  k_attn<<<4608, 256, 0, stream>>>(x, n1g, n1b, wqkvT, bq, bkv, biasx, wpT, bproj,
                                   n2g, n2b, x1b, xn);
  k_mlp<<<4608, 512, 0, stream>>>(x1b, xn, w1T, b1, dwkT, dwb, w2T, b2, outp);
}

// Round 15
// 188.061 us; speedup vs baseline: 1.0803x; 1.0065x over previous
//
#include <hip/hip_runtime.h>
#include <math.h>

typedef unsigned short u16;
typedef unsigned int u32;
typedef __attribute__((ext_vector_type(8))) unsigned short us8;
typedef __attribute__((ext_vector_type(8))) __bf16 bf16x8;
typedef __attribute__((ext_vector_type(4))) float f32x4;

#define MFMA16(a, b, c) __builtin_amdgcn_mfma_f32_16x16x32_bf16((a), (b), (c), 0, 0, 0)

static __device__ __forceinline__ float bf2f(u16 u) {
  union { u32 i; float f; } v; v.i = ((u32)u) << 16; return v.f;
}
static __device__ __forceinline__ u16 f2bf(float f) {
  __bf16 h = (__bf16)f;
  return __builtin_bit_cast(u16, h);
}
static __device__ __forceinline__ u32 pk2bf(float lo, float hi) {
  return ((u32)f2bf(hi) << 16) | (u32)f2bf(lo);
}
static __device__ __forceinline__ float lo16(u32 v) {
  union { u32 i; float f; } u; u.i = v << 16; return u.f;
}
static __device__ __forceinline__ float hi16(u32 v) {
  union { u32 i; float f; } u; u.i = v & 0xFFFF0000u; return u.f;
}
static __device__ __forceinline__ bf16x8 ldfrag(const u16* p) {
  us8 v = *reinterpret_cast<const us8*>(p);
  return __builtin_bit_cast(bf16x8, v);
}
// sigmoid-gelu: x * sigmoid(1.702x); exp folded to exp2
static __device__ __forceinline__ float gelu_s(float x) {
  return x * __builtin_amdgcn_rcpf(1.0f + __builtin_amdgcn_exp2f(-2.45564427f * x));
}

#define NTOK 147456  // 384*384
#define NWX 48
#define LOG2E 1.4426950408889634f

// ---------------------------------------------------------------------------
// Prep: transpose weights to bf16 [o][c], expand rel bias (log2-domain),
// repack dwconv weights [9][256]
// ---------------------------------------------------------------------------
__global__ __launch_bounds__(256) void k_prep(
    const float* __restrict__ wq, const float* __restrict__ wkv,
    const float* __restrict__ wproj, const float* __restrict__ w1,
    const float* __restrict__ w2, const float* __restrict__ relb,
    const float* __restrict__ dwk,
    u16* __restrict__ wqkvT, u16* __restrict__ wpT,
    u16* __restrict__ w1T, u16* __restrict__ w2T, float* __restrict__ biasx,
    float* __restrict__ dwkT)
{
  const int idx = blockIdx.x * 256 + threadIdx.x;
  const int NT = 64 * 256;
  for (int i = idx; i < 12288; i += NT) {
    int o = i >> 6, c = i & 63;
    wqkvT[i] = f2bf(o < 64 ? wq[c * 64 + o] : wkv[c * 128 + (o - 64)]);
  }
  for (int i = idx; i < 4096; i += NT) {
    int o = i >> 6, c = i & 63;
    wpT[i] = f2bf(wproj[c * 64 + o]);
  }
  for (int i = idx; i < 16384; i += NT) {
    int o = i >> 6, c = i & 63;
    w1T[i] = f2bf(w1[c * 256 + o]);
  }
  for (int i = idx; i < 16384; i += NT) {
    int o = i >> 8, c2 = i & 255;
    w2T[i] = f2bf(w2[c2 * 64 + o]);
  }
  for (int i = idx; i < 8192; i += NT) {
    int h = i >> 12, r = i & 4095, ii = r >> 6, j = r & 63;
    int dy = (ii >> 3) - (j >> 3) + 7, dx = (ii & 7) - (j & 7) + 7;
    biasx[i] = relb[(dy * 15 + dx) * 2 + h] * LOG2E;   // log2-domain
  }
  for (int i = idx; i < 2304; i += NT) {
    int q = i >> 8, c = i & 255;
    dwkT[i] = dwk[c * 9 + q];
  }
}

// softmax (log2 domain) of 4 tile-scores for one quarter of rows -> Pd (bf16)
static __device__ __forceinline__ void softmax_rows(
    const f32x4* sc, const float* biasrow_base, int i0, int lg, int lr,
    u16* Pd)
{
#pragma unroll
  for (int r = 0; r < 4; ++r) {
    const int i = i0 + lg * 4 + r;
    const float* brow = biasrow_base + i * 64;
    float pv[4];
    float mx = -1e30f;
#pragma unroll
    for (int jt = 0; jt < 4; ++jt) {
      pv[jt] = fmaf(sc[jt][r], 0.2550349f, brow[jt * 16 + lr]);  // SCALE*log2e
      mx = fmaxf(mx, pv[jt]);
    }
#pragma unroll
    for (int off = 1; off < 16; off <<= 1) mx = fmaxf(mx, __shfl_xor(mx, off));
    float sum = 0.f;
#pragma unroll
    for (int jt = 0; jt < 4; ++jt) {
      pv[jt] = __builtin_amdgcn_exp2f(pv[jt] - mx);
      sum += pv[jt];
    }
#pragma unroll
    for (int off = 1; off < 16; off <<= 1) sum += __shfl_xor(sum, off);
    const float inv = __builtin_amdgcn_rcpf(sum);
#pragma unroll
    for (int jt = 0; jt < 4; ++jt)
      Pd[i * 72 + jt * 16 + lr] = f2bf(pv[jt] * inv);
  }
}

// ---------------------------------------------------------------------------
// Kernel 1: LN1 + windowed MHSA + proj + residual -> x1b (bf16),
// plus fused LN2 -> xn (bf16). one block = 1 window, 256 thr, 3 barriers
// ---------------------------------------------------------------------------
__global__ __launch_bounds__(256, 4) void k_attn(
    const float* __restrict__ x,
    const float* __restrict__ n1g, const float* __restrict__ n1b,
    const u16* __restrict__ wqkvT, const float* __restrict__ bq,
    const float* __restrict__ bkv, const float* __restrict__ biasx,
    const u16* __restrict__ wpT, const float* __restrict__ bproj,
    const float* __restrict__ n2g, const float* __restrict__ n2b,
    u16* __restrict__ x1b, u16* __restrict__ xn)
{
  __shared__ u16 xs[64 * 72];    // LN1 out, later P (head 0)
  __shared__ u16 qsm[64 * 72];   // Q, later P (head 1)
  __shared__ u16 ksm[64 * 72];   // K, later O
  __shared__ u16 vT[64 * 72];    // V transposed [ch][token]

  const int tid = threadIdx.x;
  const int wv = tid >> 6;
  const int ln = tid & 63;
  const int lg = ln >> 4, lr = ln & 15;

  const int blk = blockIdx.x;          // 4608 blocks, 1 window each
  const int b = blk / 2304;
  const int rem = blk - b * 2304;
  const int wy = rem / NWX, wx = rem - wy * NWX;

  // ---- load window + LN1 -> xs (4 adjacent lanes own one token) ----
  {
    const int t = tid >> 2, g = tid & 3;
    const int gy = wy * 8 + (t >> 3), gx = wx * 8 + (t & 7);
    const long rowbase = ((long)b * NTOK + gy * 384 + gx) * 64;
    float loc[16];
    float s0 = 0.f, s1 = 0.f;
#pragma unroll
    for (int k = 0; k < 16; k += 4) {
      float4 v4 = *reinterpret_cast<const float4*>(x + rowbase + g * 16 + k);
      loc[k] = v4.x; loc[k + 1] = v4.y; loc[k + 2] = v4.z; loc[k + 3] = v4.w;
    }
#pragma unroll
    for (int k = 0; k < 16; ++k) { s0 += loc[k]; s1 += loc[k] * loc[k]; }
    s0 += __shfl_xor(s0, 1); s0 += __shfl_xor(s0, 2);
    s1 += __shfl_xor(s1, 1); s1 += __shfl_xor(s1, 2);
    const float m = s0 * 0.015625f;
    const float var = s1 * 0.015625f - m * m;
    const float rs = rsqrtf(var + 1e-5f);
#pragma unroll
    for (int k = 0; k < 16; ++k) {
      int c = g * 16 + k;
      xs[t * 72 + c] = f2bf((loc[k] - m) * rs * n1g[c] + n1b[c]);
    }
  }
  __syncthreads();   // barrier 1

  // ---- QKV: 3 n-groups per wave (hoisted B-frags), 4 i-tiles each ----
#pragma unroll
  for (int qq = 0; qq < 3; ++qq) {
    const int grp = 3 * wv + qq;           // 0..11 (wave-uniform)
    const int n0 = grp * 16;
    const int oc = n0 + lr;
    const float bias = (grp < 4) ? bq[oc] : bkv[oc - 64];
    bf16x8 b0 = ldfrag(&wqkvT[oc * 64 + lg * 8]);
    bf16x8 b1 = ldfrag(&wqkvT[oc * 64 + 32 + lg * 8]);
#pragma unroll
    for (int ii = 0; ii < 4; ++ii) {
      const int i0 = ii * 16;
      f32x4 acc = { bias, bias, bias, bias };
      acc = MFMA16(ldfrag(&xs[(i0 + lr) * 72 + lg * 8]), b0, acc);
      acc = MFMA16(ldfrag(&xs[(i0 + lr) * 72 + 32 + lg * 8]), b1, acc);
      const int tok0 = i0 + lg * 4;
      if (grp < 4) {
#pragma unroll
        for (int r = 0; r < 4; ++r) qsm[(tok0 + r) * 72 + oc] = f2bf(acc[r]);
      } else if (grp < 8) {
#pragma unroll
        for (int r = 0; r < 4; ++r) ksm[(tok0 + r) * 72 + (oc - 64)] = f2bf(acc[r]);
      } else {
        u32* dst = reinterpret_cast<u32*>(&vT[(oc - 128) * 72 + tok0]);
        dst[0] = pk2bf(acc[0], acc[1]);
        dst[1] = pk2bf(acc[2], acc[3]);
      }
    }
  }
  __syncthreads();   // barrier 2

  // ---- S (both heads) + softmax + P + PV -- no barriers (wave-private rows) ----
  const int i0 = wv * 16;
  f32x4 oacc[2][2];
  {
    bf16x8 aq0 = ldfrag(&qsm[(i0 + lr) * 72 + lg * 8]);
    bf16x8 aq1 = ldfrag(&qsm[(i0 + lr) * 72 + 32 + lg * 8]);
    f32x4 sc0[4], sc1[4];
#pragma unroll
    for (int jt = 0; jt < 4; ++jt) {
      f32x4 z = {};
      bf16x8 bk0 = ldfrag(&ksm[(jt * 16 + lr) * 72 + lg * 8]);
      bf16x8 bk1 = ldfrag(&ksm[(jt * 16 + lr) * 72 + 32 + lg * 8]);
      sc0[jt] = MFMA16(aq0, bk0, z);
      sc1[jt] = MFMA16(aq1, bk1, z);
    }
    softmax_rows(sc0, biasx, i0, lg, lr, xs);           // P head0 -> xs
    softmax_rows(sc1, biasx + 4096, i0, lg, lr, qsm);   // P head1 -> qsm

    // PV (reads own P rows; vT from barrier-2)
#pragma unroll
    for (int q = 0; q < 2; ++q) {
      f32x4 a0 = {}, a1 = {};
#pragma unroll
      for (int ks = 0; ks < 64; ks += 32) {
        a0 = MFMA16(ldfrag(&xs[(i0 + lr) * 72 + ks + lg * 8]),
                    ldfrag(&vT[(q * 16 + lr) * 72 + ks + lg * 8]), a0);
        a1 = MFMA16(ldfrag(&qsm[(i0 + lr) * 72 + ks + lg * 8]),
                    ldfrag(&vT[(32 + q * 16 + lr) * 72 + ks + lg * 8]), a1);
      }
      oacc[0][q] = a0;
      oacc[1][q] = a1;
    }
  }
  __syncthreads();   // barrier 3: all waves done reading ksm (S phase)

  // ---- O -> ksm (own rows) + early residual prefetch ----
  const int tok0p = i0 + lg * 4;
  const int gy0 = wy * 8 + (tok0p >> 3), gx0 = wx * 8 + (tok0p & 7);
  const long xbase = ((long)b * NTOK + gy0 * 384 + gx0) * 64;  // +64/token (r)

#pragma unroll
  for (int h = 0; h < 2; ++h)
#pragma unroll
    for (int q = 0; q < 2; ++q) {
      const int ch = h * 32 + q * 16 + lr;
#pragma unroll
      for (int r = 0; r < 4; ++r)
        ksm[(i0 + lg * 4 + r) * 72 + ch] = f2bf(oacc[h][q][r]);
    }

  // issue x residual loads now (latency hides under proj MFMAs)
  float xres[4][4];
#pragma unroll
  for (int q = 0; q < 4; ++q) {
    long idx = xbase + q * 16 + lr;
#pragma unroll
    for (int r = 0; r < 4; ++r) { xres[q][r] = x[idx]; idx += 64; }
  }
  // no barrier: proj reads only this wave's own O rows

  // ---- proj + residual -> x1b (bf16), fused LN2 -> xn (bf16) ----
  {
    float vst[4][4];
    float s[4] = {}, sq[4] = {};
#pragma unroll
    for (int q = 0; q < 4; ++q) {
      const int oc = q * 16 + lr;
      const float bp = bproj[oc];
      f32x4 acc = { bp, bp, bp, bp };
#pragma unroll
      for (int ks = 0; ks < 64; ks += 32) {
        bf16x8 ao = ldfrag(&ksm[(i0 + lr) * 72 + ks + lg * 8]);
        bf16x8 bw = ldfrag(&wpT[oc * 64 + ks + lg * 8]);
        acc = MFMA16(ao, bw, acc);
      }
      long idx = xbase + oc;
#pragma unroll
      for (int r = 0; r < 4; ++r) {
        const float v = xres[q][r] + acc[r];
        x1b[idx] = f2bf(v);
        vst[q][r] = v;
        s[r] += v; sq[r] += v * v;
        idx += 64;
      }
    }
    float ng[4], nb[4];
#pragma unroll
    for (int q = 0; q < 4; ++q) { ng[q] = n2g[q * 16 + lr]; nb[q] = n2b[q * 16 + lr]; }
#pragma unroll
    for (int r = 0; r < 4; ++r) {
      float ss = s[r], qq = sq[r];
#pragma unroll
      for (int off = 1; off < 16; off <<= 1) {
        ss += __shfl_xor(ss, off);
        qq += __shfl_xor(qq, off);
      }
      const float m = ss * 0.015625f;
      const float rs = rsqrtf(qq * 0.015625f - m * m + 1e-5f);
      const long idxn = xbase + r * 64 + lr;
#pragma unroll
      for (int q = 0; q < 4; ++q)
        xn[idxn + q * 16] = f2bf((vst[q][r] - m) * rs * ng[q] + nb[q]);
    }
  }
}

// ---------------------------------------------------------------------------
// Kernel 2: stage xn halo + fc1 + gelu + dwconv3x3 + gelu + fc2 + residual
// HID chunked by 64; 38.9KB LDS -> 4 blocks/CU; interior fast path;
// XCD-aware block swizzle (8 XCDs, 4608 % 8 == 0 -> bijective)
// ---------------------------------------------------------------------------
__global__ __launch_bounds__(512, 8) void k_mlp(
    const u16* __restrict__ x1b, const u16* __restrict__ xn,
    const u16* __restrict__ w1T, const float* __restrict__ pb1,
    const float* __restrict__ dwkT, const float* __restrict__ dwb,
    const u16* __restrict__ w2T, const float* __restrict__ pb2,
    float* __restrict__ out)
{
  __shared__ u16 xln[112 * 72];    // LN2'd halo tile (bf16); rows>=100 garbage ok
  __shared__ u16 htbT[64 * 102];   // gelu(fc1) chunk, TRANSPOSED [ch][pos]
  __shared__ u16 g2[64 * 72];      // gelu(dwconv) chunk (bf16) [token][ch]
  __shared__ float flag[112];      // boundary blocks only

  const int tid = threadIdx.x;
  const int wave = tid >> 6, ln = tid & 63;
  const int lg = ln >> 4, lr = ln & 15;
  // XCD-aware swizzle: each XCD gets a contiguous 576-tile band (12 tile-rows)
  const int blk0 = blockIdx.x;
  const int blk = (blk0 & 7) * 576 + (blk0 >> 3);
  const int b = blk / 2304;
  const int rem = blk - b * 2304;
  const int ty0 = (rem / NWX) * 8, tx0 = (rem - (rem / NWX) * NWX) * 8;
  const bool interior = (ty0 > 0) && (ty0 < 376) && (tx0 > 0) && (tx0 < 376);

  const int hh = ln >> 5, c2 = ln & 31;
  const long hbase = (long)b * NTOK + (ty0 - 1) * 384 + (tx0 - 1);

  // incremental p/10 decomposition: p = j*16 + wave*2 + hh
  {
    int p = wave * 2 + hh;                 // 0..15
    int ry = (p >= 10) ? 1 : 0;
    int rx = p - ry * 10;
    if (interior) {
#pragma unroll
      for (int j = 0; j < 7; ++j) {
        if (p < 100) {
          const long tok = hbase + ry * 384 + rx;
          *reinterpret_cast<u32*>(&xln[p * 72 + c2 * 2]) =
              *reinterpret_cast<const u32*>(&xn[tok * 64 + c2 * 2]);
        }
        p += 16; rx += 6; ry += 1;
        if (rx >= 10) { rx -= 10; ry += 1; }
      }
    } else {
      if (tid < 112) {
        float f = 0.f;
        if (tid < 100) {
          const int py = ty0 + tid / 10 - 1, px = tx0 + tid % 10 - 1;
          if (py >= 0 && py < 384 && px >= 0 && px < 384) f = 1.f;
        }
        flag[tid] = f;
      }
#pragma unroll
      for (int j = 0; j < 7; ++j) {
        if (p < 112) {
          u32 v = 0;
          if (p < 100) {
            const int py = ty0 - 1 + ry, px = tx0 - 1 + rx;
            if ((unsigned)py < 384u && (unsigned)px < 384u) {
              const long tok = hbase + ry * 384 + rx;
              v = *reinterpret_cast<const u32*>(&xn[tok * 64 + c2 * 2]);
            }
          }
          *reinterpret_cast<u32*>(&xln[p * 72 + c2 * 2]) = v;
        }
        p += 16; rx += 6; ry += 1;
        if (rx >= 10) { rx -= 10; ry += 1; }
      }
    }
  }
  __syncthreads();   // xln (+flag) ready

  // wave-constant tile coordinates
  const int n0f = (wave & 3) * 16;       // fc1 col-tile base (const per wave)
  const int i0b = (wave >> 2) * 16;      // fc1 row-tile base: 0 or 16
  const int ocf = n0f + lr;
  const int o0  = (wave >> 1) * 16;      // fc2 out-col tile
  const int i0q = ((wave * 2) & 3) * 16; // fc2 row tile base (q=0)
  const int oc2 = o0 + lr;
  const float fc2_b = pb2[oc2];
  f32x4 facc[2] = { { fc2_b, fc2_b, fc2_b, fc2_b }, { fc2_b, fc2_b, fc2_b, fc2_b } };

#pragma unroll 1
  for (int ch = 0; ch < 4; ++ch) {
    // ---- fc1 chunk + gelu -> htbT ----
    {
      const u16* wbase = &w1T[(ch * 64 + ocf) * 64 + lg * 8];
      bf16x8 wb0 = ldfrag(wbase);
      bf16x8 wb1 = ldfrag(wbase + 32);
      const float bias1 = pb1[ch * 64 + ocf];
      if (interior) {
#pragma unroll
        for (int k = 0; k < 4; ++k) {
          const int i0 = i0b + k * 32;
          if (i0 < 112) {
            f32x4 acc = { bias1, bias1, bias1, bias1 };
            acc = MFMA16(ldfrag(&xln[(i0 + lr) * 72 + lg * 8]), wb0, acc);
            acc = MFMA16(ldfrag(&xln[(i0 + lr) * 72 + 32 + lg * 8]), wb1, acc);
            const int p0 = i0 + lg * 4;
            if (p0 < 100) {
              u32* dst = reinterpret_cast<u32*>(&htbT[ocf * 102 + p0]);
              dst[0] = pk2bf(gelu_s(acc[0]), gelu_s(acc[1]));
              dst[1] = pk2bf(gelu_s(acc[2]), gelu_s(acc[3]));
            }
          }
        }
      } else {
#pragma unroll
        for (int k = 0; k < 4; ++k) {
          const int i0 = i0b + k * 32;
          if (i0 < 112) {
            f32x4 acc = { bias1, bias1, bias1, bias1 };
            acc = MFMA16(ldfrag(&xln[(i0 + lr) * 72 + lg * 8]), wb0, acc);
            acc = MFMA16(ldfrag(&xln[(i0 + lr) * 72 + 32 + lg * 8]), wb1, acc);
            const int p0 = i0 + lg * 4;
            if (p0 < 100) {
              float g0 = gelu_s(acc[0]) * flag[p0 + 0];
              float g1 = gelu_s(acc[1]) * flag[p0 + 1];
              float g2v = gelu_s(acc[2]) * flag[p0 + 2];
              float g3 = gelu_s(acc[3]) * flag[p0 + 3];
              u32* dst = reinterpret_cast<u32*>(&htbT[ocf * 102 + p0]);
              dst[0] = pk2bf(g0, g1);
              dst[1] = pk2bf(g2v, g3);
            }
          }
        }
      }
    }
    __syncthreads();

    // ---- dwconv 3x3 + gelu -> g2 (wave = token row, lane = channel) ----
    {
      const int gch = ch * 64 + ln;
      float wk[9];
      const float db = dwb[gch];
#pragma unroll
      for (int q = 0; q < 9; ++q) wk[q] = dwkT[q * 256 + gch];   // coalesced
      const u16* rowbase = &htbT[ln * 102];
      const u32* r0 = reinterpret_cast<const u32*>(rowbase + (wave + 0) * 10);
      const u32* r1 = reinterpret_cast<const u32*>(rowbase + (wave + 1) * 10);
      const u32* r2 = reinterpret_cast<const u32*>(rowbase + (wave + 2) * 10);
      u32 v;
      float a0,b0,c0,d0, a1,b1,c1,d1, a2,b2,c2,d2;
      v = r0[0]; a0 = lo16(v); b0 = hi16(v);
      v = r0[1]; c0 = lo16(v); d0 = hi16(v);
      v = r1[0]; a1 = lo16(v); b1 = hi16(v);
      v = r1[1]; c1 = lo16(v); d1 = hi16(v);
      v = r2[0]; a2 = lo16(v); b2 = hi16(v);
      v = r2[1]; c2 = lo16(v); d2 = hi16(v);
#pragma unroll
      for (int s = 0; s < 4; ++s) {
        float e0 = db + a0 * wk[0] + b0 * wk[1] + c0 * wk[2]
                      + a1 * wk[3] + b1 * wk[4] + c1 * wk[5]
                      + a2 * wk[6] + b2 * wk[7] + c2 * wk[8];
        float e1 = db + b0 * wk[0] + c0 * wk[1] + d0 * wk[2]
                      + b1 * wk[3] + c1 * wk[4] + d1 * wk[5]
                      + b2 * wk[6] + c2 * wk[7] + d2 * wk[8];
        g2[(wave * 8 + 2 * s) * 72 + ln]     = f2bf(gelu_s(e0));
        g2[(wave * 8 + 2 * s + 1) * 72 + ln] = f2bf(gelu_s(e1));
        if (s < 3) {
          v = r0[s + 2]; a0 = c0; b0 = d0; c0 = lo16(v); d0 = hi16(v);
          v = r1[s + 2]; a1 = c1; b1 = d1; c1 = lo16(v); d1 = hi16(v);
          v = r2[s + 2]; a2 = c2; b2 = d2; c2 = lo16(v); d2 = hi16(v);
        }
      }
    }
    __syncthreads();

    // ---- fc2 partial accumulate (B-frags hoisted, shared by q=0,1) ----
    {
      const u16* wbase2 = &w2T[oc2 * 256 + ch * 64 + lg * 8];
      bf16x8 bw0 = ldfrag(wbase2);
      bf16x8 bw1 = ldfrag(wbase2 + 32);
#pragma unroll
      for (int q = 0; q < 2; ++q) {
        const int i0 = i0q + q * 16;
        bf16x8 ag0 = ldfrag(&g2[(i0 + lr) * 72 + lg * 8]);
        bf16x8 ag1 = ldfrag(&g2[(i0 + lr) * 72 + 32 + lg * 8]);
        facc[q] = MFMA16(ag0, bw0, facc[q]);
        facc[q] = MFMA16(ag1, bw1, facc[q]);
      }
    }
  }

  // ---- epilogue: + bf16 residual -> out ----
#pragma unroll
  for (int q = 0; q < 2; ++q) {
    const int tok0 = i0q + q * 16 + lg * 4;
    const int gy = ty0 + (tok0 >> 3), gx = tx0 + (tok0 & 7);
    long idx = ((long)b * NTOK + gy * 384 + gx) * 64 + oc2;
#pragma unroll
    for (int r = 0; r < 4; ++r) {
      out[idx] = bf2f(x1b[idx]) + facc[q][r];
      idx += 64;
    }
  }
}

extern "C" void kernel_launch(void* const* d_in, const int* in_sizes, int n_in,
                              void* d_out, int out_size, void* d_ws, size_t ws_size,
                              hipStream_t stream) {
  const float* x     = (const float*)d_in[0];
  const float* n1g   = (const float*)d_in[1];
  const float* n1b   = (const float*)d_in[2];
  const float* wq    = (const float*)d_in[3];
  const float* bq    = (const float*)d_in[4];
  const float* wkv   = (const float*)d_in[5];
  const float* bkv   = (const float*)d_in[6];
  const float* relb  = (const float*)d_in[7];
  const float* wproj = (const float*)d_in[8];
  const float* bproj = (const float*)d_in[9];
  const float* n2g   = (const float*)d_in[10];
  const float* n2b   = (const float*)d_in[11];
  const float* w1    = (const float*)d_in[12];
  const float* b1    = (const float*)d_in[13];
  const float* dwk   = (const float*)d_in[14];
  const float* dwb   = (const float*)d_in[15];
  const float* w2    = (const float*)d_in[16];
  const float* b2    = (const float*)d_in[17];

  char* ws = (char*)d_ws;
  u16*    wqkvT = (u16*)ws;                    //    24576 B
  u16*    wpT   = (u16*)(ws + 24576);          //     8192 B
  u16*    w1T   = (u16*)(ws + 32768);          //    32768 B
  u16*    w2T   = (u16*)(ws + 65536);          //    32768 B
  float*  biasx = (float*)(ws + 98304);        //    32768 B
  float*  dwkT  = (float*)(ws + 131072);       //     9216 B (pad to 16384)
  u16*    x1b   = (u16*)(ws + 147456);         // 37748736 B (bf16 residual)
  u16*    xn    = (u16*)(ws + 37896192);       // 37748736 B (bf16 LN2 out)
  float*  outp  = (float*)d_out;               // total ws use ~75.6 MB

  k_prep<<<64, 256, 0, stream>>>(wq, wkv, wproj, w1, w2, relb, dwk,
                                 wqkvT, wpT, w1T, w2T, biasx, dwkT);
  k_attn<<<4608, 256, 0, stream>>>(x, n1g, n1b, wqkvT, bq, bkv, biasx, wpT, bproj,
                                   n2g, n2b, x1b, xn);
  k_mlp<<<4608, 512, 0, stream>>>(x1b, xn, w1T, b1, dwkT, dwb, w2T, b2, outp);
}

// Round 16
// 186.304 us; speedup vs baseline: 1.0905x; 1.0094x over previous
//
#include <hip/hip_runtime.h>
#include <math.h>

typedef unsigned short u16;
typedef unsigned int u32;
typedef __attribute__((ext_vector_type(8))) unsigned short us8;
typedef __attribute__((ext_vector_type(8))) __bf16 bf16x8;
typedef __attribute__((ext_vector_type(4))) float f32x4;

#define MFMA16(a, b, c) __builtin_amdgcn_mfma_f32_16x16x32_bf16((a), (b), (c), 0, 0, 0)

static __device__ __forceinline__ float bf2f(u16 u) {
  union { u32 i; float f; } v; v.i = ((u32)u) << 16; return v.f;
}
static __device__ __forceinline__ u16 f2bf(float f) {
  __bf16 h = (__bf16)f;
  return __builtin_bit_cast(u16, h);
}
static __device__ __forceinline__ u32 pk2bf(float lo, float hi) {
  return ((u32)f2bf(hi) << 16) | (u32)f2bf(lo);
}
static __device__ __forceinline__ float lo16(u32 v) {
  union { u32 i; float f; } u; u.i = v << 16; return u.f;
}
static __device__ __forceinline__ float hi16(u32 v) {
  union { u32 i; float f; } u; u.i = v & 0xFFFF0000u; return u.f;
}
static __device__ __forceinline__ bf16x8 ldfrag(const u16* p) {
  us8 v = *reinterpret_cast<const us8*>(p);
  return __builtin_bit_cast(bf16x8, v);
}
// sigmoid-gelu: x * sigmoid(1.702x); exp folded to exp2
static __device__ __forceinline__ float gelu_s(float x) {
  return x * __builtin_amdgcn_rcpf(1.0f + __builtin_amdgcn_exp2f(-2.45564427f * x));
}

#define NTOK 147456  // 384*384
#define NWX 48
#define LOG2E 1.4426950408889634f

// ---------------------------------------------------------------------------
// Prep: transpose weights to bf16 [o][c], expand rel bias (log2-domain),
// repack dwconv weights [9][256]
// ---------------------------------------------------------------------------
__global__ __launch_bounds__(256) void k_prep(
    const float* __restrict__ wq, const float* __restrict__ wkv,
    const float* __restrict__ wproj, const float* __restrict__ w1,
    const float* __restrict__ w2, const float* __restrict__ relb,
    const float* __restrict__ dwk,
    u16* __restrict__ wqkvT, u16* __restrict__ wpT,
    u16* __restrict__ w1T, u16* __restrict__ w2T, float* __restrict__ biasx,
    float* __restrict__ dwkT)
{
  const int idx = blockIdx.x * 256 + threadIdx.x;
  const int NT = 64 * 256;
  for (int i = idx; i < 12288; i += NT) {
    int o = i >> 6, c = i & 63;
    wqkvT[i] = f2bf(o < 64 ? wq[c * 64 + o] : wkv[c * 128 + (o - 64)]);
  }
  for (int i = idx; i < 4096; i += NT) {
    int o = i >> 6, c = i & 63;
    wpT[i] = f2bf(wproj[c * 64 + o]);
  }
  for (int i = idx; i < 16384; i += NT) {
    int o = i >> 6, c = i & 63;
    w1T[i] = f2bf(w1[c * 256 + o]);
  }
  for (int i = idx; i < 16384; i += NT) {
    int o = i >> 8, c2 = i & 255;
    w2T[i] = f2bf(w2[c2 * 64 + o]);
  }
  for (int i = idx; i < 8192; i += NT) {
    int h = i >> 12, r = i & 4095, ii = r >> 6, j = r & 63;
    int dy = (ii >> 3) - (j >> 3) + 7, dx = (ii & 7) - (j & 7) + 7;
    biasx[i] = relb[(dy * 15 + dx) * 2 + h] * LOG2E;   // log2-domain
  }
  for (int i = idx; i < 2304; i += NT) {
    int q = i >> 8, c = i & 255;
    dwkT[i] = dwk[c * 9 + q];
  }
}

// softmax (log2 domain) of 4 tile-scores for one quarter of rows -> Pd (bf16)
static __device__ __forceinline__ void softmax_rows(
    const f32x4* sc, const float* biasrow_base, int i0, int lg, int lr,
    u16* Pd)
{
#pragma unroll
  for (int r = 0; r < 4; ++r) {
    const int i = i0 + lg * 4 + r;
    const float* brow = biasrow_base + i * 64;
    float pv[4];
    float mx = -1e30f;
#pragma unroll
    for (int jt = 0; jt < 4; ++jt) {
      pv[jt] = fmaf(sc[jt][r], 0.2550349f, brow[jt * 16 + lr]);  // SCALE*log2e
      mx = fmaxf(mx, pv[jt]);
    }
#pragma unroll
    for (int off = 1; off < 16; off <<= 1) mx = fmaxf(mx, __shfl_xor(mx, off));
    float sum = 0.f;
#pragma unroll
    for (int jt = 0; jt < 4; ++jt) {
      pv[jt] = __builtin_amdgcn_exp2f(pv[jt] - mx);
      sum += pv[jt];
    }
#pragma unroll
    for (int off = 1; off < 16; off <<= 1) sum += __shfl_xor(sum, off);
    const float inv = __builtin_amdgcn_rcpf(sum);
#pragma unroll
    for (int jt = 0; jt < 4; ++jt)
      Pd[i * 72 + jt * 16 + lr] = f2bf(pv[jt] * inv);
  }
}

// ---------------------------------------------------------------------------
// Kernel 1: LN1 + windowed MHSA + proj + residual -> x1b (bf16),
// plus fused LN2 -> xn (bf16). one block = 1 window, 256 thr, 2 barriers
// ---------------------------------------------------------------------------
__global__ __launch_bounds__(256, 4) void k_attn(
    const float* __restrict__ x,
    const float* __restrict__ n1g, const float* __restrict__ n1b,
    const u16* __restrict__ wqkvT, const float* __restrict__ bq,
    const float* __restrict__ bkv, const float* __restrict__ biasx,
    const u16* __restrict__ wpT, const float* __restrict__ bproj,
    const float* __restrict__ n2g, const float* __restrict__ n2b,
    u16* __restrict__ x1b, u16* __restrict__ xn)
{
  __shared__ u16 xs[64 * 72];    // LN1 out, later P (head 0), later O (own rows)
  __shared__ u16 qsm[64 * 72];   // Q, later P (head 1)
  __shared__ u16 ksm[64 * 72];   // K (read-only after barrier 2)
  __shared__ u16 vT[64 * 72];    // V transposed [ch][token]

  const int tid = threadIdx.x;
  const int wv = tid >> 6;
  const int ln = tid & 63;
  const int lg = ln >> 4, lr = ln & 15;

  const int blk = blockIdx.x;          // 4608 blocks, 1 window each
  const int b = blk / 2304;
  const int rem = blk - b * 2304;
  const int wy = rem / NWX, wx = rem - wy * NWX;

  // ---- load window + LN1 -> xs (4 adjacent lanes own one token) ----
  {
    const int t = tid >> 2, g = tid & 3;
    const int gy = wy * 8 + (t >> 3), gx = wx * 8 + (t & 7);
    const long rowbase = ((long)b * NTOK + gy * 384 + gx) * 64;
    float loc[16];
    float s0 = 0.f, s1 = 0.f;
#pragma unroll
    for (int k = 0; k < 16; k += 4) {
      float4 v4 = *reinterpret_cast<const float4*>(x + rowbase + g * 16 + k);
      loc[k] = v4.x; loc[k + 1] = v4.y; loc[k + 2] = v4.z; loc[k + 3] = v4.w;
    }
#pragma unroll
    for (int k = 0; k < 16; ++k) { s0 += loc[k]; s1 += loc[k] * loc[k]; }
    s0 += __shfl_xor(s0, 1); s0 += __shfl_xor(s0, 2);
    s1 += __shfl_xor(s1, 1); s1 += __shfl_xor(s1, 2);
    const float m = s0 * 0.015625f;
    const float var = s1 * 0.015625f - m * m;
    const float rs = rsqrtf(var + 1e-5f);
#pragma unroll
    for (int k = 0; k < 16; ++k) {
      int c = g * 16 + k;
      xs[t * 72 + c] = f2bf((loc[k] - m) * rs * n1g[c] + n1b[c]);
    }
  }
  __syncthreads();   // barrier 1

  // ---- QKV: 3 n-groups per wave (hoisted B-frags), 4 i-tiles each ----
#pragma unroll
  for (int qq = 0; qq < 3; ++qq) {
    const int grp = 3 * wv + qq;           // 0..11 (wave-uniform)
    const int n0 = grp * 16;
    const int oc = n0 + lr;
    const float bias = (grp < 4) ? bq[oc] : bkv[oc - 64];
    bf16x8 b0 = ldfrag(&wqkvT[oc * 64 + lg * 8]);
    bf16x8 b1 = ldfrag(&wqkvT[oc * 64 + 32 + lg * 8]);
#pragma unroll
    for (int ii = 0; ii < 4; ++ii) {
      const int i0 = ii * 16;
      f32x4 acc = { bias, bias, bias, bias };
      acc = MFMA16(ldfrag(&xs[(i0 + lr) * 72 + lg * 8]), b0, acc);
      acc = MFMA16(ldfrag(&xs[(i0 + lr) * 72 + 32 + lg * 8]), b1, acc);
      const int tok0 = i0 + lg * 4;
      if (grp < 4) {
#pragma unroll
        for (int r = 0; r < 4; ++r) qsm[(tok0 + r) * 72 + oc] = f2bf(acc[r]);
      } else if (grp < 8) {
#pragma unroll
        for (int r = 0; r < 4; ++r) ksm[(tok0 + r) * 72 + (oc - 64)] = f2bf(acc[r]);
      } else {
        u32* dst = reinterpret_cast<u32*>(&vT[(oc - 128) * 72 + tok0]);
        dst[0] = pk2bf(acc[0], acc[1]);
        dst[1] = pk2bf(acc[2], acc[3]);
      }
    }
  }
  __syncthreads();   // barrier 2 (last block-wide barrier)

  // ---- S (both heads) + softmax + P + PV -- wave-private rows from here on ----
  const int i0 = wv * 16;
  f32x4 oacc[2][2];
  {
    bf16x8 aq0 = ldfrag(&qsm[(i0 + lr) * 72 + lg * 8]);
    bf16x8 aq1 = ldfrag(&qsm[(i0 + lr) * 72 + 32 + lg * 8]);
    f32x4 sc0[4], sc1[4];
#pragma unroll
    for (int jt = 0; jt < 4; ++jt) {
      f32x4 z = {};
      bf16x8 bk0 = ldfrag(&ksm[(jt * 16 + lr) * 72 + lg * 8]);
      bf16x8 bk1 = ldfrag(&ksm[(jt * 16 + lr) * 72 + 32 + lg * 8]);
      sc0[jt] = MFMA16(aq0, bk0, z);
      sc1[jt] = MFMA16(aq1, bk1, z);
    }
    softmax_rows(sc0, biasx, i0, lg, lr, xs);           // P head0 -> xs (own rows)
    softmax_rows(sc1, biasx + 4096, i0, lg, lr, qsm);   // P head1 -> qsm (own rows)

    // PV (reads own P rows; vT read-only)
#pragma unroll
    for (int q = 0; q < 2; ++q) {
      f32x4 a0 = {}, a1 = {};
#pragma unroll
      for (int ks = 0; ks < 64; ks += 32) {
        a0 = MFMA16(ldfrag(&xs[(i0 + lr) * 72 + ks + lg * 8]),
                    ldfrag(&vT[(q * 16 + lr) * 72 + ks + lg * 8]), a0);
        a1 = MFMA16(ldfrag(&qsm[(i0 + lr) * 72 + ks + lg * 8]),
                    ldfrag(&vT[(32 + q * 16 + lr) * 72 + ks + lg * 8]), a1);
      }
      oacc[0][q] = a0;
      oacc[1][q] = a1;
    }
  }
  // no barrier: O goes into this wave's own (now dead) P rows of xs

  // ---- O -> xs (own rows) + early residual prefetch ----
  const int tok0p = i0 + lg * 4;
  const int gy0 = wy * 8 + (tok0p >> 3), gx0 = wx * 8 + (tok0p & 7);
  const long xbase = ((long)b * NTOK + gy0 * 384 + gx0) * 64;  // +64/token (r)

#pragma unroll
  for (int h = 0; h < 2; ++h)
#pragma unroll
    for (int q = 0; q < 2; ++q) {
      const int ch = h * 32 + q * 16 + lr;
#pragma unroll
      for (int r = 0; r < 4; ++r)
        xs[(i0 + lg * 4 + r) * 72 + ch] = f2bf(oacc[h][q][r]);
    }

  // issue x residual loads now (latency hides under proj MFMAs)
  float xres[4][4];
#pragma unroll
  for (int q = 0; q < 4; ++q) {
    long idx = xbase + q * 16 + lr;
#pragma unroll
    for (int r = 0; r < 4; ++r) { xres[q][r] = x[idx]; idx += 64; }
  }

  // ---- proj + residual -> x1b (bf16), fused LN2 -> xn (bf16) ----
  {
    float vst[4][4];
    float s[4] = {}, sq[4] = {};
#pragma unroll
    for (int q = 0; q < 4; ++q) {
      const int oc = q * 16 + lr;
      const float bp = bproj[oc];
      f32x4 acc = { bp, bp, bp, bp };
#pragma unroll
      for (int ks = 0; ks < 64; ks += 32) {
        bf16x8 ao = ldfrag(&xs[(i0 + lr) * 72 + ks + lg * 8]);
        bf16x8 bw = ldfrag(&wpT[oc * 64 + ks + lg * 8]);
        acc = MFMA16(ao, bw, acc);
      }
      long idx = xbase + oc;
#pragma unroll
      for (int r = 0; r < 4; ++r) {
        const float v = xres[q][r] + acc[r];
        x1b[idx] = f2bf(v);
        vst[q][r] = v;
        s[r] += v; sq[r] += v * v;
        idx += 64;
      }
    }
    float ng[4], nb[4];
#pragma unroll
    for (int q = 0; q < 4; ++q) { ng[q] = n2g[q * 16 + lr]; nb[q] = n2b[q * 16 + lr]; }
#pragma unroll
    for (int r = 0; r < 4; ++r) {
      float ss = s[r], qq = sq[r];
#pragma unroll
      for (int off = 1; off < 16; off <<= 1) {
        ss += __shfl_xor(ss, off);
        qq += __shfl_xor(qq, off);
      }
      const float m = ss * 0.015625f;
      const float rs = rsqrtf(qq * 0.015625f - m * m + 1e-5f);
      const long idxn = xbase + r * 64 + lr;
#pragma unroll
      for (int q = 0; q < 4; ++q)
        xn[idxn + q * 16] = f2bf((vst[q][r] - m) * rs * ng[q] + nb[q]);
    }
  }
}

// ---------------------------------------------------------------------------
// Kernel 2: stage xn halo + fc1 + gelu + dwconv3x3 + gelu + fc2 + residual
// HID chunked by 64; 38.9KB LDS -> 4 blocks/CU; interior fast path;
// XCD-aware block swizzle (8 XCDs, 4608 % 8 == 0 -> bijective)
// ---------------------------------------------------------------------------
__global__ __launch_bounds__(512, 8) void k_mlp(
    const u16* __restrict__ x1b, const u16* __restrict__ xn,
    const u16* __restrict__ w1T, const float* __restrict__ pb1,
    const float* __restrict__ dwkT, const float* __restrict__ dwb,
    const u16* __restrict__ w2T, const float* __restrict__ pb2,
    float* __restrict__ out)
{
  __shared__ u16 xln[112 * 72];    // LN2'd halo tile (bf16); rows>=100 garbage ok
  __shared__ u16 htbT[64 * 102];   // gelu(fc1) chunk, TRANSPOSED [ch][pos]
  __shared__ u16 g2[64 * 72];      // gelu(dwconv) chunk (bf16) [token][ch]
  __shared__ float flag[112];      // boundary blocks only

  const int tid = threadIdx.x;
  const int wave = tid >> 6, ln = tid & 63;
  const int lg = ln >> 4, lr = ln & 15;
  // XCD-aware swizzle: each XCD gets a contiguous 576-tile band (12 tile-rows)
  const int blk0 = blockIdx.x;
  const int blk = (blk0 & 7) * 576 + (blk0 >> 3);
  const int b = blk / 2304;
  const int rem = blk - b * 2304;
  const int ty0 = (rem / NWX) * 8, tx0 = (rem - (rem / NWX) * NWX) * 8;
  const bool interior = (ty0 > 0) && (ty0 < 376) && (tx0 > 0) && (tx0 < 376);

  const int hh = ln >> 5, c2 = ln & 31;
  const long hbase = (long)b * NTOK + (ty0 - 1) * 384 + (tx0 - 1);

  // incremental p/10 decomposition: p = j*16 + wave*2 + hh
  {
    int p = wave * 2 + hh;                 // 0..15
    int ry = (p >= 10) ? 1 : 0;
    int rx = p - ry * 10;
    if (interior) {
      // j = 0..5: p <= 95 < 100 always -> unguarded
#pragma unroll
      for (int j = 0; j < 6; ++j) {
        const long tok = hbase + ry * 384 + rx;
        *reinterpret_cast<u32*>(&xln[p * 72 + c2 * 2]) =
            *reinterpret_cast<const u32*>(&xn[tok * 64 + c2 * 2]);
        p += 16; rx += 6; ry += 1;
        if (rx >= 10) { rx -= 10; ry += 1; }
      }
      if (p < 100) {   // j = 6
        const long tok = hbase + ry * 384 + rx;
        *reinterpret_cast<u32*>(&xln[p * 72 + c2 * 2]) =
            *reinterpret_cast<const u32*>(&xn[tok * 64 + c2 * 2]);
      }
    } else {
      if (tid < 112) {
        float f = 0.f;
        if (tid < 100) {
          const int py = ty0 + tid / 10 - 1, px = tx0 + tid % 10 - 1;
          if (py >= 0 && py < 384 && px >= 0 && px < 384) f = 1.f;
        }
        flag[tid] = f;
      }
#pragma unroll
      for (int j = 0; j < 7; ++j) {
        u32 v = 0;
        if (p < 100) {
          const int py = ty0 - 1 + ry, px = tx0 - 1 + rx;
          if ((unsigned)py < 384u && (unsigned)px < 384u) {
            const long tok = hbase + ry * 384 + rx;
            v = *reinterpret_cast<const u32*>(&xn[tok * 64 + c2 * 2]);
          }
        }
        if (p < 112)
          *reinterpret_cast<u32*>(&xln[p * 72 + c2 * 2]) = v;
        p += 16; rx += 6; ry += 1;
        if (rx >= 10) { rx -= 10; ry += 1; }
      }
    }
  }
  __syncthreads();   // xln (+flag) ready

  // wave-constant tile coordinates
  const int n0f = (wave & 3) * 16;       // fc1 col-tile base (const per wave)
  const int i0b = (wave >> 2) * 16;      // fc1 row-tile base: 0 or 16
  const int ocf = n0f + lr;
  const int o0  = (wave >> 1) * 16;      // fc2 out-col tile
  const int i0q = ((wave * 2) & 3) * 16; // fc2 row tile base (q=0)
  const int oc2 = o0 + lr;
  const float fc2_b = pb2[oc2];
  f32x4 facc[2] = { { fc2_b, fc2_b, fc2_b, fc2_b }, { fc2_b, fc2_b, fc2_b, fc2_b } };

#pragma unroll 1
  for (int ch = 0; ch < 4; ++ch) {
    // ---- fc1 chunk + gelu -> htbT ----
    {
      const u16* wbase = &w1T[(ch * 64 + ocf) * 64 + lg * 8];
      bf16x8 wb0 = ldfrag(wbase);
      bf16x8 wb1 = ldfrag(wbase + 32);
      const float bias1 = pb1[ch * 64 + ocf];
      if (interior) {
#pragma unroll
        for (int k = 0; k < 4; ++k) {
          const int i0 = i0b + k * 32;
          if (i0 < 112) {
            f32x4 acc = { bias1, bias1, bias1, bias1 };
            acc = MFMA16(ldfrag(&xln[(i0 + lr) * 72 + lg * 8]), wb0, acc);
            acc = MFMA16(ldfrag(&xln[(i0 + lr) * 72 + 32 + lg * 8]), wb1, acc);
            const int p0 = i0 + lg * 4;
            if (p0 < 100) {
              u32* dst = reinterpret_cast<u32*>(&htbT[ocf * 102 + p0]);
              dst[0] = pk2bf(gelu_s(acc[0]), gelu_s(acc[1]));
              dst[1] = pk2bf(gelu_s(acc[2]), gelu_s(acc[3]));
            }
          }
        }
      } else {
#pragma unroll
        for (int k = 0; k < 4; ++k) {
          const int i0 = i0b + k * 32;
          if (i0 < 112) {
            f32x4 acc = { bias1, bias1, bias1, bias1 };
            acc = MFMA16(ldfrag(&xln[(i0 + lr) * 72 + lg * 8]), wb0, acc);
            acc = MFMA16(ldfrag(&xln[(i0 + lr) * 72 + 32 + lg * 8]), wb1, acc);
            const int p0 = i0 + lg * 4;
            if (p0 < 100) {
              float g0 = gelu_s(acc[0]) * flag[p0 + 0];
              float g1 = gelu_s(acc[1]) * flag[p0 + 1];
              float g2v = gelu_s(acc[2]) * flag[p0 + 2];
              float g3 = gelu_s(acc[3]) * flag[p0 + 3];
              u32* dst = reinterpret_cast<u32*>(&htbT[ocf * 102 + p0]);
              dst[0] = pk2bf(g0, g1);
              dst[1] = pk2bf(g2v, g3);
            }
          }
        }
      }
    }
    __syncthreads();

    // ---- dwconv 3x3 + gelu -> g2 (wave = token row, lane = channel) ----
    {
      const int gch = ch * 64 + ln;
      float wk[9];
      const float db = dwb[gch];
#pragma unroll
      for (int q = 0; q < 9; ++q) wk[q] = dwkT[q * 256 + gch];   // coalesced
      const u16* rowbase = &htbT[ln * 102];
      const u32* r0 = reinterpret_cast<const u32*>(rowbase + (wave + 0) * 10);
      const u32* r1 = reinterpret_cast<const u32*>(rowbase + (wave + 1) * 10);
      const u32* r2 = reinterpret_cast<const u32*>(rowbase + (wave + 2) * 10);
      u32 v;
      float a0,b0,c0,d0, a1,b1,c1,d1, a2,b2,c2,d2;
      v = r0[0]; a0 = lo16(v); b0 = hi16(v);
      v = r0[1]; c0 = lo16(v); d0 = hi16(v);
      v = r1[0]; a1 = lo16(v); b1 = hi16(v);
      v = r1[1]; c1 = lo16(v); d1 = hi16(v);
      v = r2[0]; a2 = lo16(v); b2 = hi16(v);
      v = r2[1]; c2 = lo16(v); d2 = hi16(v);
#pragma unroll
      for (int s = 0; s < 4; ++s) {
        float e0 = db + a0 * wk[0] + b0 * wk[1] + c0 * wk[2]
                      + a1 * wk[3] + b1 * wk[4] + c1 * wk[5]
                      + a2 * wk[6] + b2 * wk[7] + c2 * wk[8];
        float e1 = db + b0 * wk[0] + c0 * wk[1] + d0 * wk[2]
                      + b1 * wk[3] + c1 * wk[4] + d1 * wk[5]
                      + b2 * wk[6] + c2 * wk[7] + d2 * wk[8];
        g2[(wave * 8 + 2 * s) * 72 + ln]     = f2bf(gelu_s(e0));
        g2[(wave * 8 + 2 * s + 1) * 72 + ln] = f2bf(gelu_s(e1));
        if (s < 3) {
          v = r0[s + 2]; a0 = c0; b0 = d0; c0 = lo16(v); d0 = hi16(v);
          v = r1[s + 2]; a1 = c1; b1 = d1; c1 = lo16(v); d1 = hi16(v);
          v = r2[s + 2]; a2 = c2; b2 = d2; c2 = lo16(v); d2 = hi16(v);
        }
      }
    }
    __syncthreads();

    // ---- fc2 partial accumulate (B-frags hoisted, shared by q=0,1) ----
    {
      const u16* wbase2 = &w2T[oc2 * 256 + ch * 64 + lg * 8];
      bf16x8 bw0 = ldfrag(wbase2);
      bf16x8 bw1 = ldfrag(wbase2 + 32);
#pragma unroll
      for (int q = 0; q < 2; ++q) {
        const int i0 = i0q + q * 16;
        bf16x8 ag0 = ldfrag(&g2[(i0 + lr) * 72 + lg * 8]);
        bf16x8 ag1 = ldfrag(&g2[(i0 + lr) * 72 + 32 + lg * 8]);
        facc[q] = MFMA16(ag0, bw0, facc[q]);
        facc[q] = MFMA16(ag1, bw1, facc[q]);
      }
    }
  }

  // ---- epilogue: + bf16 residual -> out ----
#pragma unroll
  for (int q = 0; q < 2; ++q) {
    const int tok0 = i0q + q * 16 + lg * 4;
    const int gy = ty0 + (tok0 >> 3), gx = tx0 + (tok0 & 7);
    long idx = ((long)b * NTOK + gy * 384 + gx) * 64 + oc2;
#pragma unroll
    for (int r = 0; r < 4; ++r) {
      out[idx] = bf2f(x1b[idx]) + facc[q][r];
      idx += 64;
    }
  }
}

extern "C" void kernel_launch(void* const* d_in, const int* in_sizes, int n_in,
                              void* d_out, int out_size, void* d_ws, size_t ws_size,
                              hipStream_t stream) {
  const float* x     = (const float*)d_in[0];
  const float* n1g   = (const float*)d_in[1];
  const float* n1b   = (const float*)d_in[2];
  const float* wq    = (const float*)d_in[3];
  const float* bq    = (const float*)d_in[4];
  const float* wkv   = (const float*)d_in[5];
  const float* bkv   = (const float*)d_in[6];
  const float* relb  = (const float*)d_in[7];
  const float* wproj = (const float*)d_in[8];
  const float* bproj = (const float*)d_in[9];
  const float* n2g   = (const float*)d_in[10];
  const float* n2b   = (const float*)d_in[11];
  const float* w1    = (const float*)d_in[12];
  const float* b1    = (const float*)d_in[13];
  const float* dwk   = (const float*)d_in[14];
  const float* dwb   = (const float*)d_in[15];
  const float* w2    = (const float*)d_in[16];
  const float* b2    = (const float*)d_in[17];

  char* ws = (char*)d_ws;
  u16*    wqkvT = (u16*)ws;                    //    24576 B
  u16*    wpT   = (u16*)(ws + 24576);          //     8192 B
  u16*    w1T   = (u16*)(ws + 32768);          //    32768 B
  u16*    w2T   = (u16*)(ws + 65536);          //    32768 B
  float*  biasx = (float*)(ws + 98304);        //    32768 B
  float*  dwkT  = (float*)(ws + 131072);       //     9216 B (pad to 16384)
  u16*    x1b   = (u16*)(ws + 147456);         // 37748736 B (bf16 residual)
  u16*    xn    = (u16*)(ws + 37896192);       // 37748736 B (bf16 LN2 out)
  float*  outp  = (float*)d_out;               // total ws use ~75.6 MB

  k_prep<<<64, 256, 0, stream>>>(wq, wkv, wproj, w1, w2, relb, dwk,
                                 wqkvT, wpT, w1T, w2T, biasx, dwkT);
  k_attn<<<4608, 256, 0, stream>>>(x, n1g, n1b, wqkvT, bq, bkv, biasx, wpT, bproj,
                                   n2g, n2b, x1b, xn);
  k_mlp<<<4608, 512, 0, stream>>>(x1b, xn, w1T, b1, dwkT, dwb, w2T, b2, outp);
}